// Round 3
// baseline (335.670 us; speedup 1.0000x reference)
//
#include <hip/hip_runtime.h>

typedef __attribute__((ext_vector_type(4))) float f32x4;
typedef __attribute__((ext_vector_type(8))) short bf16x8;

#define MFMA16(a, b, c) __builtin_amdgcn_mfma_f32_16x16x32_bf16((a), (b), (c), 0, 0, 0)
#define LOG2E 1.44269504088896340736f

static __device__ __forceinline__ float bf2f(short u) {
  unsigned x = ((unsigned)(unsigned short)u) << 16;
  return __builtin_bit_cast(float, x);
}
static __device__ __forceinline__ short f2bf(float f) {
  unsigned u = __builtin_bit_cast(unsigned, f);
  u += 0x7fffu + ((u >> 16) & 1u);
  return (short)(u >> 16);
}
// global -> LDS direct DMA, 16B per lane. LDS dest is wave-uniform base +
// lane*16 (guide §5); swizzle done on the GLOBAL source address (rule #21).
static __device__ __forceinline__ void gll16(const void* g, void* l) {
  __builtin_amdgcn_global_load_lds(
      (const __attribute__((address_space(1))) unsigned*)(unsigned long long)g,
      (__attribute__((address_space(3))) unsigned*)(unsigned)(unsigned long long)l,
      16, 0, 0);
}

// ---------------- f32 -> bf16 conversion (vectorized, G13) ----------------
__global__ void __launch_bounds__(256) cvt_kernel(const float* __restrict__ src,
                                                  short* __restrict__ dst,
                                                  long long n) {
  long long i = ((long long)blockIdx.x * 256 + threadIdx.x) * 8;
  const long long stride = (long long)gridDim.x * 256 * 8;
  for (; i < n; i += stride) {
    f32x4 a = *(const f32x4*)(src + i);
    f32x4 b = *(const f32x4*)(src + i + 4);
    bf16x8 o;
    o[0] = f2bf(a[0]); o[1] = f2bf(a[1]); o[2] = f2bf(a[2]); o[3] = f2bf(a[3]);
    o[4] = f2bf(b[0]); o[5] = f2bf(b[1]); o[6] = f2bf(b[2]); o[7] = f2bf(b[3]);
    *(bf16x8*)(dst + i) = o;
  }
}

__global__ void bias_concat(const float* __restrict__ bq, const float* __restrict__ bk,
                            const float* __restrict__ bv, float* __restrict__ ball) {
  const int i = blockIdx.x * 256 + threadIdx.x;
  if (i < 3584) ball[i] = bq[i];
  else if (i < 4096) ball[i] = bk[i - 3584];
  else if (i < 4608) ball[i] = bv[i - 4096];
}

// ---------------- RoPE cos/sin table: [2048][64] ----------------
__global__ void rope_table(const int* __restrict__ pos, float* __restrict__ ctab,
                           float* __restrict__ stab) {
  const int s = blockIdx.x;
  const int i = threadIdx.x;  // 0..63
  const float p = (float)pos[s];
  const float ang = p * exp2f(-(float)i * 0.3114307588956902f);
  ctab[s * 64 + i] = cosf(ang);
  stab[s * 64 + i] = sinf(ang);
}

// In-place RoPE on q/k regions of qkv[2048][4608]. Q heads (h<28) are
// pre-scaled by SCALE*LOG2E so attention scores come out in exp2-domain.
__global__ void __launch_bounds__(256) rope_apply(short* __restrict__ qkv,
                                                  const float* __restrict__ ctab,
                                                  const float* __restrict__ stab) {
  const int idx = blockIdx.x * 256 + threadIdx.x;  // 2048*32*8
  const int c = idx & 7;
  const int h = (idx >> 3) & 31;
  const int s = idx >> 8;
  const float qs = (h < 28) ? (0.08838834764831845f * LOG2E) : 1.0f;
  short* base = qkv + (size_t)s * 4608 + h * 128 + c * 8;
  bf16x8 lo = *(bf16x8*)base;
  bf16x8 hi = *(bf16x8*)(base + 64);
  const float* cp = ctab + s * 64 + c * 8;
  const float* sp = stab + s * 64 + c * 8;
  bf16x8 lo2, hi2;
#pragma unroll
  for (int j = 0; j < 8; ++j) {
    const float x = bf2f(lo[j]), y = bf2f(hi[j]);
    const float cv = cp[j], sv = sp[j];
    lo2[j] = f2bf((x * cv - y * sv) * qs);
    hi2[j] = f2bf((y * cv + x * sv) * qs);
  }
  *(bf16x8*)base = lo2;
  *(bf16x8*)(base + 64) = hi2;
}

// V region of qkv -> V^T [4][128][2048]
__global__ void __launch_bounds__(256) v_transpose(const short* __restrict__ qkv,
                                                   short* __restrict__ vtb) {
  __shared__ short t[64 * 48];
  const int dt = blockIdx.x, st = blockIdx.y, kv = blockIdx.z;
  const int tid = threadIdx.x;
  {
    const int r = tid >> 2, c8 = tid & 3;
    const bf16x8 v = *(const bf16x8*)(qkv + (size_t)(st * 64 + r) * 4608 + 4096 +
                                      kv * 128 + dt * 32 + c8 * 8);
    *(bf16x8*)(t + r * 48 + c8 * 8) = v;
  }
  __syncthreads();
  {
    const int d = tid >> 3, c = tid & 7;
    bf16x8 v;
#pragma unroll
    for (int i = 0; i < 8; ++i) v[i] = t[(c * 8 + i) * 48 + d];
    *(bf16x8*)(vtb + ((size_t)kv * 128 + dt * 32 + d) * 2048 + st * 64 + c * 8) = v;
  }
}

// ---------------- 256x256 8-phase bf16 GEMM (T1+T2+T3+T4+T5) ----------------
// C[M=2048,N] = A[2048,K] * B[N,K]^T (+bias). 8 waves (2M x 4N), BK=64,
// 2 K-tiles per iter, double-buffered 128KB LDS.
// LDS row layouts (permuted so per-phase consumption is 64-row-batch-aligned):
//   A: ldsrow = rh*128 + wm*64 + r6   (global row = wm*128 + rh*64 + r6)
//   B: ldsrow = ch*128 + wn*32 + c5   (global col = wn*64 + ch*32 + c5)
// Phase order per K-tile: (rh,ch) = (0,0),(1,0),(0,1),(1,1).
// Freed-after: Bch0 after p1, Arh0 after p2, Arh1/Bch1 after p3.
// Stage schedule (iter i computes tiles t0=2i (buf0), t1=2i+1 (buf1)):
//   P0:A23(t1,b1) P1:B23(t1,b1) P2:B01(k2,b0) P3:A01(k2,b0)
//   P4:A23(k2,b0) P5:B23(k2,b0) P6:B01(k3,b1) P7:A01(k3,b1)   [k2=2i+2,k3=2i+3]
// vmcnt(4) at end of P3/P7 (vmcnt(0) at P3 of last iter).
template <bool BIAS, bool OUTBF>
__global__ void __launch_bounds__(512, 2)
gemm8(const short* __restrict__ A, const short* __restrict__ B,
      const float* __restrict__ bias, void* __restrict__ outp, int N, int K) {
  __shared__ short As[2][256 * 64];
  __shared__ short Bs[2][256 * 64];
  const int per = (int)gridDim.x >> 3;  // grid % 8 == 0
  const int bid = (int)blockIdx.x;
  const int tile = (bid & 7) * per + (bid >> 3);  // bijective XCD swizzle
  const int tm = (tile & 7) << 8;                 // M = 2048 -> 8 M-tiles
  const int tn = (tile >> 3) << 8;
  const int tid = (int)threadIdx.x;
  const int wave = tid >> 6, lane = tid & 63;
  const int l15 = lane & 15, g = lane >> 4;
  const int wm = wave >> 2, wn = wave & 3;
  const int srow = lane >> 3, sslot = lane & 7;

  f32x4 acc[8][4] = {};

#define STAGE_A(b, kt, j)                                                       \
  {                                                                             \
    const int lr = (j) * 64 + wave * 8 + srow;                                  \
    const int grow = ((lr >> 6) & 1) * 128 + (lr >> 7) * 64 + (lr & 63);        \
    const int cs = sslot ^ (lr & 7);                                            \
    gll16(A + (size_t)(tm + grow) * K + (kt) * 64 + cs * 8,                     \
          &As[b][((j) * 64 + wave * 8) * 64]);                                  \
  }
#define STAGE_B(b, kt, j)                                                       \
  {                                                                             \
    const int lr = (j) * 64 + wave * 8 + srow;                                  \
    const int gcol = ((lr >> 5) & 3) * 64 + (lr >> 7) * 32 + (lr & 31);         \
    const int cs = sslot ^ (lr & 7);                                            \
    gll16(B + (size_t)(tn + gcol) * K + (kt) * 64 + cs * 8,                     \
          &Bs[b][((j) * 64 + wave * 8) * 64]);                                  \
  }
#define PHASE(b, rh, chh, STAGES, WAITC)                                        \
  {                                                                             \
    bf16x8 af[4][2], bfr[2][2];                                                 \
    _Pragma("unroll") for (int mq = 0; mq < 4; ++mq) {                          \
      const int ar = (rh)*128 + wm * 64 + mq * 16 + l15;                        \
      _Pragma("unroll") for (int kk = 0; kk < 2; ++kk) {                        \
        const int c = (kk * 4 + g) ^ (ar & 7);                                  \
        af[mq][kk] = *(const bf16x8*)(&As[b][ar * 64 + c * 8]);                 \
      }                                                                         \
    }                                                                           \
    _Pragma("unroll") for (int nq = 0; nq < 2; ++nq) {                          \
      const int br = (chh)*128 + wn * 32 + nq * 16 + l15;                       \
      _Pragma("unroll") for (int kk = 0; kk < 2; ++kk) {                        \
        const int c = (kk * 4 + g) ^ (br & 7);                                  \
        bfr[nq][kk] = *(const bf16x8*)(&Bs[b][br * 64 + c * 8]);                \
      }                                                                         \
    }                                                                           \
    STAGES;                                                                     \
    __builtin_amdgcn_s_barrier();                                               \
    asm volatile("s_waitcnt lgkmcnt(0)" ::: "memory");                          \
    __builtin_amdgcn_sched_barrier(0);                                          \
    __builtin_amdgcn_s_setprio(1);                                              \
    _Pragma("unroll") for (int mq = 0; mq < 4; ++mq)                            \
      _Pragma("unroll") for (int nq = 0; nq < 2; ++nq) {                        \
        acc[(rh)*4 + mq][(chh)*2 + nq] =                                        \
            MFMA16(af[mq][0], bfr[nq][0], acc[(rh)*4 + mq][(chh)*2 + nq]);      \
        acc[(rh)*4 + mq][(chh)*2 + nq] =                                        \
            MFMA16(af[mq][1], bfr[nq][1], acc[(rh)*4 + mq][(chh)*2 + nq]);      \
      }                                                                         \
    __builtin_amdgcn_s_setprio(0);                                              \
    WAITC;                                                                      \
    __builtin_amdgcn_s_barrier();                                               \
  }

  // prologue: tile0 fully (8 loads), then tile1's B01+A01 (4 loads)
  STAGE_A(0, 0, 0); STAGE_A(0, 0, 1); STAGE_A(0, 0, 2); STAGE_A(0, 0, 3);
  STAGE_B(0, 0, 0); STAGE_B(0, 0, 1); STAGE_B(0, 0, 2); STAGE_B(0, 0, 3);
  STAGE_B(1, 1, 0); STAGE_B(1, 1, 1);
  STAGE_A(1, 1, 0); STAGE_A(1, 1, 1);
  asm volatile("s_waitcnt vmcnt(4)" ::: "memory");
  __builtin_amdgcn_s_barrier();

  const int L = K >> 7;
  for (int i = 0; i < L; ++i) {
    const int k1 = 2 * i + 1, k2 = 2 * i + 2, k3 = 2 * i + 3;
    const bool more = (i < L - 1);
    PHASE(0, 0, 0, { STAGE_A(1, k1, 2); STAGE_A(1, k1, 3); }, {});
    PHASE(0, 1, 0, { STAGE_B(1, k1, 2); STAGE_B(1, k1, 3); }, {});
    PHASE(0, 0, 1, { if (more) { STAGE_B(0, k2, 0); STAGE_B(0, k2, 1); } }, {});
    PHASE(0, 1, 1, { if (more) { STAGE_A(0, k2, 0); STAGE_A(0, k2, 1); } },
          { if (more) { asm volatile("s_waitcnt vmcnt(4)" ::: "memory"); }
            else      { asm volatile("s_waitcnt vmcnt(0)" ::: "memory"); } });
    PHASE(1, 0, 0, { if (more) { STAGE_A(0, k2, 2); STAGE_A(0, k2, 3); } }, {});
    PHASE(1, 1, 0, { if (more) { STAGE_B(0, k2, 2); STAGE_B(0, k2, 3); } }, {});
    PHASE(1, 0, 1, { if (more) { STAGE_B(1, k3, 0); STAGE_B(1, k3, 1); } }, {});
    PHASE(1, 1, 1, { if (more) { STAGE_A(1, k3, 0); STAGE_A(1, k3, 1); } },
          { asm volatile("s_waitcnt vmcnt(4)" ::: "memory"); });
  }
#undef STAGE_A
#undef STAGE_B
#undef PHASE

  // epilogue: C/D frag layout col=lane&15, row=g*4+r; permuted tile mapping
#pragma unroll
  for (int m = 0; m < 8; ++m) {
    const int row0 = tm + wm * 128 + (m >> 2) * 64 + (m & 3) * 16 + g * 4;
#pragma unroll
    for (int n = 0; n < 4; ++n) {
      const int col = tn + wn * 64 + (n >> 1) * 32 + (n & 1) * 16 + l15;
      const float bv = BIAS ? bias[col] : 0.0f;
#pragma unroll
      for (int r = 0; r < 4; ++r) {
        const float v = acc[m][n][r] + bv;
        if (OUTBF) ((short*)outp)[(size_t)(row0 + r) * N + col] = f2bf(v);
        else       ((float*)outp)[(size_t)(row0 + r) * N + col] = v;
      }
    }
  }
}

// ---------------- flash attention, 2-phase pipelined, paired q-tiles --------
__global__ void __launch_bounds__(256) attn_kernel(const short* __restrict__ qkv,
                                                   const short* __restrict__ vtb,
                                                   short* __restrict__ outb) {
  const int lid = (int)blockIdx.x + ((int)blockIdx.y << 4);
  const int kvh = (lid & 7) >> 1;
  const int u = ((lid >> 3) << 1) + (lid & 1);  // 0..111 within kv group
  const int head = kvh * 7 + (u >> 4);
  const int qtA = u & 15, qtB = 31 - qtA;

  const int tid = threadIdx.x;
  const int lane = tid & 63, wave = tid >> 6;
  const int l15 = lane & 15, g = lane >> 4;

  __shared__ short Ks[2][64 * 128];
  __shared__ short Vs[2][128 * 64];
  __shared__ short Ps[4][16 * 64];

  const short* kbase = qkv + 3584 + kvh * 128;
  const short* vbase = vtb + (size_t)kvh * 128 * 2048;
  const float NINF = -__builtin_inff();

  bf16x8 qf[4];
  f32x4 o[8];
  float mrun[4], lrun[4];

#define LOADQ(qt)                                                                  \
  {                                                                                \
    const short* qptr =                                                            \
        qkv + (size_t)((qt)*64 + wave * 16 + l15) * 4608 + head * 128 + g * 8;     \
    _Pragma("unroll") for (int ds = 0; ds < 4; ++ds) qf[ds] =                      \
        *(const bf16x8*)(qptr + ds * 32);                                          \
  }
#define RESET()                                                                    \
  {                                                                                \
    _Pragma("unroll") for (int nd = 0; nd < 8; ++nd) o[nd] = f32x4{0.f,0.f,0.f,0.f}; \
    _Pragma("unroll") for (int r = 0; r < 4; ++r) { mrun[r] = NINF; lrun[r] = 0.f; } \
  }
#define STAGE(kv, b)                                                               \
  {                                                                                \
    _Pragma("unroll") for (int it = 0; it < 4; ++it) {                             \
      const int chunk = it * 256 + tid;                                            \
      const int row = chunk >> 4, sc = (chunk & 15) ^ (row & 7);                   \
      gll16(kbase + (size_t)((kv)*64 + row) * 4608 + sc * 8,                       \
            &Ks[b][(it * 256 + wave * 64) * 8]);                                   \
    }                                                                              \
    _Pragma("unroll") for (int it = 0; it < 4; ++it) {                             \
      const int chunk = it * 256 + tid;                                            \
      const int row = chunk >> 3, sc = (chunk & 7) ^ (row & 7);                    \
      gll16(vbase + (size_t)row * 2048 + (kv)*64 + sc * 8,                         \
            &Vs[b][(it * 256 + wave * 64) * 8]);                                   \
    }                                                                              \
  }

  RESET();
  LOADQ(qtA);
  STAGE(0, 0);
  __syncthreads();
  int cur = 0;

  for (int s = 0; s < 33; ++s) {
    if (s < 32) {
      const int sn = s + 1;
      const int kvn = (sn <= qtA) ? sn : sn - qtA - 1;
      STAGE(kvn, cur ^ 1);
    }
    const int qt = (s <= qtA) ? qtA : qtB;
    const int kv = (s <= qtA) ? s : s - qtA - 1;
    const bool diag = (s == qtA) || (s == 32);

    f32x4 sf[4] = {};
    __builtin_amdgcn_s_setprio(1);
#pragma unroll
    for (int n = 0; n < 4; ++n) {
      const int krow = n * 16 + l15;
#pragma unroll
      for (int ds = 0; ds < 4; ++ds) {
        const int c = (ds * 4 + g) ^ (krow & 7);
        const bf16x8 kf = *(const bf16x8*)(&Ks[cur][krow * 128 + c * 8]);
        sf[n] = MFMA16(qf[ds], kf, sf[n]);
      }
    }
    __builtin_amdgcn_s_setprio(0);

    if (diag) {
#pragma unroll
      for (int r = 0; r < 4; ++r) {
        const int qr = qt * 64 + wave * 16 + g * 4 + r;
#pragma unroll
        for (int n = 0; n < 4; ++n)
          if (kv * 64 + n * 16 + l15 > qr) sf[n][r] = NINF;
      }
    }
    float pmax[4];
#pragma unroll
    for (int r = 0; r < 4; ++r)
      pmax[r] = fmaxf(fmaxf(sf[0][r], sf[1][r]), fmaxf(sf[2][r], sf[3][r]));
    const bool need = (pmax[0] > mrun[0] + 8.f) || (pmax[1] > mrun[1] + 8.f) ||
                      (pmax[2] > mrun[2] + 8.f) || (pmax[3] > mrun[3] + 8.f);
    if (__any(need)) {
#pragma unroll
      for (int r = 0; r < 4; ++r) {
        float mx = pmax[r];
        mx = fmaxf(mx, __shfl_xor(mx, 1));
        mx = fmaxf(mx, __shfl_xor(mx, 2));
        mx = fmaxf(mx, __shfl_xor(mx, 4));
        mx = fmaxf(mx, __shfl_xor(mx, 8));
        const float mnew = fmaxf(mrun[r], mx);
        const float alpha = exp2f(mrun[r] - mnew);
        mrun[r] = mnew;
        lrun[r] *= alpha;
#pragma unroll
        for (int nd = 0; nd < 8; ++nd) o[nd][r] *= alpha;
      }
    }
#pragma unroll
    for (int n = 0; n < 4; ++n) {
#pragma unroll
      for (int r = 0; r < 4; ++r) {
        const float p = exp2f(sf[n][r] - mrun[r]);
        lrun[r] += p;
        const int prow = g * 4 + r, key = n * 16 + l15;
        const int cp = (key >> 3) ^ (prow & 7);
        Ps[wave][prow * 64 + cp * 8 + (key & 7)] = f2bf(p);
      }
    }
    bf16x8 pf[2];
#pragma unroll
    for (int ksl = 0; ksl < 2; ++ksl) {
      const int c = (ksl * 4 + g) ^ (l15 & 7);
      pf[ksl] = *(const bf16x8*)(&Ps[wave][l15 * 64 + c * 8]);
    }
    __builtin_amdgcn_s_setprio(1);
#pragma unroll
    for (int nd = 0; nd < 8; ++nd) {
      const int vrow = nd * 16 + l15;
#pragma unroll
      for (int ksl = 0; ksl < 2; ++ksl) {
        const int c = (ksl * 4 + g) ^ (vrow & 7);
        const bf16x8 vf = *(const bf16x8*)(&Vs[cur][vrow * 64 + c * 8]);
        o[nd] = MFMA16(pf[ksl], vf, o[nd]);
      }
    }
    __builtin_amdgcn_s_setprio(0);

    if (diag) {
      float inv[4];
#pragma unroll
      for (int r = 0; r < 4; ++r) {
        float sum = lrun[r];
        sum += __shfl_xor(sum, 1);
        sum += __shfl_xor(sum, 2);
        sum += __shfl_xor(sum, 4);
        sum += __shfl_xor(sum, 8);
        inv[r] = 1.0f / sum;
      }
#pragma unroll
      for (int nd = 0; nd < 8; ++nd) {
#pragma unroll
        for (int r = 0; r < 4; ++r) {
          const int qr = qt * 64 + wave * 16 + g * 4 + r;
          outb[(size_t)qr * 3584 + head * 128 + nd * 16 + l15] = f2bf(o[nd][r] * inv[r]);
        }
      }
      if (s == qtA) {
        RESET();
        LOADQ(qtB);
      }
    }
    __syncthreads();
    cur ^= 1;
  }
#undef LOADQ
#undef RESET
#undef STAGE
}

extern "C" void kernel_launch(void* const* d_in, const int* in_sizes, int n_in,
                              void* d_out, int out_size, void* d_ws, size_t ws_size,
                              hipStream_t stream) {
  const float* h  = (const float*)d_in[0];
  const int* pos  = (const int*)d_in[1];
  const float* Wq = (const float*)d_in[2];
  const float* bq = (const float*)d_in[3];
  const float* Wk = (const float*)d_in[4];
  const float* bk = (const float*)d_in[5];
  const float* Wv = (const float*)d_in[6];
  const float* bv = (const float*)d_in[7];
  const float* Wo = (const float*)d_in[8];
  float* out = (float*)d_out;

  char* w = (char*)d_ws;
  short* hbf  = (short*)w; w += (size_t)2048 * 3584 * 2;
  short* Wall = (short*)w; w += (size_t)4608 * 3584 * 2;
  float* ball = (float*)w; w += 4608 * 4;
  short* qkvp = (short*)w; w += (size_t)2048 * 4608 * 2;
  float* ctab = (float*)w; w += 2048 * 64 * 4;
  float* stab = (float*)w; w += 2048 * 64 * 4;
  short* vtb  = (short*)w; w += (size_t)4 * 128 * 2048 * 2;
  short* attnb = hbf;
  short* Wob = Wall;

  cvt_kernel<<<2048, 256, 0, stream>>>(h, hbf, (long long)2048 * 3584);
  cvt_kernel<<<2048, 256, 0, stream>>>(Wq, Wall, (long long)3584 * 3584);
  cvt_kernel<<<512, 256, 0, stream>>>(Wk, Wall + (size_t)3584 * 3584, (long long)512 * 3584);
  cvt_kernel<<<512, 256, 0, stream>>>(Wv, Wall + (size_t)4096 * 3584, (long long)512 * 3584);
  bias_concat<<<18, 256, 0, stream>>>(bq, bk, bv, ball);
  rope_table<<<2048, 64, 0, stream>>>(pos, ctab, stab);

  gemm8<true, true><<<144, 512, 0, stream>>>(hbf, Wall, ball, qkvp, 4608, 3584);
  rope_apply<<<2048, 256, 0, stream>>>(qkvp, ctab, stab);
  v_transpose<<<dim3(4, 32, 4), 256, 0, stream>>>(qkvp, vtb);
  cvt_kernel<<<2048, 256, 0, stream>>>(Wo, Wob, (long long)3584 * 3584);

  attn_kernel<<<dim3(16, 28), 256, 0, stream>>>(qkvp, vtb, attnb);

  gemm8<false, false><<<112, 512, 0, stream>>>(attnb, Wob, nullptr, out, 3584, 3584);
}

// Round 4
// 288.421 us; speedup vs baseline: 1.1638x; 1.1638x over previous
//
#include <hip/hip_runtime.h>

typedef __attribute__((ext_vector_type(4))) float f32x4;
typedef __attribute__((ext_vector_type(16))) float f32x16;
typedef __attribute__((ext_vector_type(8))) short bf16x8;

#define MFMA16(a, b, c) __builtin_amdgcn_mfma_f32_16x16x32_bf16((a), (b), (c), 0, 0, 0)
#define MFMA32(a, b, c) __builtin_amdgcn_mfma_f32_32x32x16_bf16((a), (b), (c), 0, 0, 0)
#define LOG2E 1.44269504088896340736f

static __device__ __forceinline__ float bf2f(short u) {
  unsigned x = ((unsigned)(unsigned short)u) << 16;
  return __builtin_bit_cast(float, x);
}
static __device__ __forceinline__ short f2bf(float f) {
  unsigned u = __builtin_bit_cast(unsigned, f);
  u += 0x7fffu + ((u >> 16) & 1u);
  return (short)(u >> 16);
}
// global -> LDS direct DMA, 16B per lane. LDS dest is wave-uniform base +
// lane*16 (guide §5); swizzle done on the GLOBAL source address (rule #21).
static __device__ __forceinline__ void gll16(const void* g, void* l) {
  __builtin_amdgcn_global_load_lds(
      (const __attribute__((address_space(1))) unsigned*)(unsigned long long)g,
      (__attribute__((address_space(3))) unsigned*)(unsigned)(unsigned long long)l,
      16, 0, 0);
}

// ---------------- f32 -> bf16 conversion (vectorized, G13) ----------------
__global__ void __launch_bounds__(256) cvt_kernel(const float* __restrict__ src,
                                                  short* __restrict__ dst,
                                                  long long n) {
  long long i = ((long long)blockIdx.x * 256 + threadIdx.x) * 8;
  const long long stride = (long long)gridDim.x * 256 * 8;
  for (; i < n; i += stride) {
    f32x4 a = *(const f32x4*)(src + i);
    f32x4 b = *(const f32x4*)(src + i + 4);
    bf16x8 o;
    o[0] = f2bf(a[0]); o[1] = f2bf(a[1]); o[2] = f2bf(a[2]); o[3] = f2bf(a[3]);
    o[4] = f2bf(b[0]); o[5] = f2bf(b[1]); o[6] = f2bf(b[2]); o[7] = f2bf(b[3]);
    *(bf16x8*)(dst + i) = o;
  }
}

__global__ void bias_concat(const float* __restrict__ bq, const float* __restrict__ bk,
                            const float* __restrict__ bv, float* __restrict__ ball) {
  const int i = blockIdx.x * 256 + threadIdx.x;
  if (i < 3584) ball[i] = bq[i];
  else if (i < 4096) ball[i] = bk[i - 3584];
  else if (i < 4608) ball[i] = bv[i - 4096];
}

// ---------------- RoPE cos/sin table: [2048][64] ----------------
__global__ void rope_table(const int* __restrict__ pos, float* __restrict__ ctab,
                           float* __restrict__ stab) {
  const int s = blockIdx.x;
  const int i = threadIdx.x;  // 0..63
  const float p = (float)pos[s];
  const float ang = p * exp2f(-(float)i * 0.3114307588956902f);
  ctab[s * 64 + i] = cosf(ang);
  stab[s * 64 + i] = sinf(ang);
}

// In-place RoPE on q/k regions of qkv[2048][4608]. Q heads (h<28) are
// pre-scaled by SCALE*LOG2E so attention scores come out in exp2-domain.
__global__ void __launch_bounds__(256) rope_apply(short* __restrict__ qkv,
                                                  const float* __restrict__ ctab,
                                                  const float* __restrict__ stab) {
  const int idx = blockIdx.x * 256 + threadIdx.x;  // 2048*32*8
  const int c = idx & 7;
  const int h = (idx >> 3) & 31;
  const int s = idx >> 8;
  const float qs = (h < 28) ? (0.08838834764831845f * LOG2E) : 1.0f;
  short* base = qkv + (size_t)s * 4608 + h * 128 + c * 8;
  bf16x8 lo = *(bf16x8*)base;
  bf16x8 hi = *(bf16x8*)(base + 64);
  const float* cp = ctab + s * 64 + c * 8;
  const float* sp = stab + s * 64 + c * 8;
  bf16x8 lo2, hi2;
#pragma unroll
  for (int j = 0; j < 8; ++j) {
    const float x = bf2f(lo[j]), y = bf2f(hi[j]);
    const float cv = cp[j], sv = sp[j];
    lo2[j] = f2bf((x * cv - y * sv) * qs);
    hi2[j] = f2bf((y * cv + x * sv) * qs);
  }
  *(bf16x8*)base = lo2;
  *(bf16x8*)(base + 64) = hi2;
}

// V region of qkv -> V^T [4][128][2048]
__global__ void __launch_bounds__(256) v_transpose(const short* __restrict__ qkv,
                                                   short* __restrict__ vtb) {
  __shared__ short t[64 * 48];
  const int dt = blockIdx.x, st = blockIdx.y, kv = blockIdx.z;
  const int tid = threadIdx.x;
  {
    const int r = tid >> 2, c8 = tid & 3;
    const bf16x8 v = *(const bf16x8*)(qkv + (size_t)(st * 64 + r) * 4608 + 4096 +
                                      kv * 128 + dt * 32 + c8 * 8);
    *(bf16x8*)(t + r * 48 + c8 * 8) = v;
  }
  __syncthreads();
  {
    const int d = tid >> 3, c = tid & 7;
    bf16x8 v;
#pragma unroll
    for (int i = 0; i < 8; ++i) v[i] = t[(c * 8 + i) * 48 + d];
    *(bf16x8*)(vtb + ((size_t)kv * 128 + dt * 32 + d) * 2048 + st * 64 + c * 8) = v;
  }
}

// ------------- bf16 GEMM, 32x32x16 MFMA, BK=32, 4-deep LDS pipeline --------
// C[M=2048,N] = A[M,K]*B[N,K]^T (+bias). BM x 256 tile, 8 waves (2M x 4N).
// Per K-tile/wave: 12 ds_read_b128 feed 16 MFMA (frag reuse within the
// full m x n sweep). One barrier per K-tile; vmcnt(CALLS) counted wait (T4)
// -> 2 K-tiles of global_load_lds always in flight, never drained.
// LDS layout: 2 rows per 128B line, chunk slot = (row&1)*4 + (c ^ (line&3));
// staging linear-dest with inverse-permuted global source (rule #21);
// frag reads 2-way per quarter-wave (free).
template <int BM, bool BIAS, bool OUTBF>
__global__ void __launch_bounds__(512, 1)
gemm32(const short* __restrict__ A, const short* __restrict__ B,
       const float* __restrict__ bias, void* __restrict__ outp, int N, int K) {
  constexpr int MQ = BM / 64;        // 32-row frags per wave (256->4, 128->2)
  constexpr int ACALLS = BM / 128;   // 8KB stage calls for A tile
  constexpr int CALLS = ACALLS + 2;  // + 2 for B tile (256x32x2B = 16KB)
  constexpr int MT = 2048 / BM;
  __shared__ short As[4][BM * 32];
  __shared__ short Bs[4][256 * 32];
  const int per = (int)gridDim.x >> 3;
  const int bid = (int)blockIdx.x;
  const int tile = (bid & 7) * per + (bid >> 3);  // bijective XCD swizzle
  const int tm = (tile % MT) * BM;
  const int tn = (tile / MT) * 256;
  const int tid = (int)threadIdx.x;
  const int wave = tid >> 6, lane = tid & 63;
  const int l31 = lane & 31, g2 = lane >> 5;
  const int wm = wave >> 2, wn = wave & 3;

  f32x16 acc[MQ][2] = {};

#define STAGE_T(buf, kt)                                                        \
  {                                                                             \
    _Pragma("unroll") for (int j = 0; j < ACALLS; ++j) {                        \
      const int L = j * 512 + tid;                                              \
      const int row = ((L >> 3) << 1) + ((L >> 2) & 1);                         \
      const int c = (L & 3) ^ ((L >> 3) & 3);                                   \
      gll16(A + (size_t)(tm + row) * K + (kt) * 32 + c * 8,                     \
            &As[buf][(j * 512 + wave * 64) * 8]);                               \
    }                                                                           \
    _Pragma("unroll") for (int j = 0; j < 2; ++j) {                             \
      const int L = j * 512 + tid;                                              \
      const int row = ((L >> 3) << 1) + ((L >> 2) & 1);                         \
      const int c = (L & 3) ^ ((L >> 3) & 3);                                   \
      gll16(B + (size_t)(tn + row) * K + (kt) * 32 + c * 8,                     \
            &Bs[buf][(j * 512 + wave * 64) * 8]);                               \
    }                                                                           \
  }
#define KSTEP(bufi)                                                             \
  {                                                                             \
    bf16x8 af[MQ][2], bfr[2][2];                                                \
    _Pragma("unroll") for (int mq = 0; mq < MQ; ++mq)                           \
      _Pragma("unroll") for (int kk = 0; kk < 2; ++kk) {                        \
        const int row = wm * (BM / 2) + mq * 32 + l31;                          \
        const int line = row >> 1, c = kk * 2 + g2;                             \
        af[mq][kk] = *(const bf16x8*)(&As[bufi][line * 64 + (row & 1) * 32 +    \
                                                ((c ^ (line & 3)) * 8)]);       \
      }                                                                         \
    _Pragma("unroll") for (int nq = 0; nq < 2; ++nq)                            \
      _Pragma("unroll") for (int kk = 0; kk < 2; ++kk) {                        \
        const int row = wn * 64 + nq * 32 + l31;                                \
        const int line = row >> 1, c = kk * 2 + g2;                             \
        bfr[nq][kk] = *(const bf16x8*)(&Bs[bufi][line * 64 + (row & 1) * 32 +   \
                                                 ((c ^ (line & 3)) * 8)]);      \
      }                                                                         \
    asm volatile("s_waitcnt lgkmcnt(0)" ::: "memory");                          \
    __builtin_amdgcn_sched_barrier(0);                                          \
    __builtin_amdgcn_s_setprio(1);                                              \
    _Pragma("unroll") for (int mq = 0; mq < MQ; ++mq)                           \
      _Pragma("unroll") for (int nq = 0; nq < 2; ++nq) {                        \
        acc[mq][nq] = MFMA32(af[mq][0], bfr[nq][0], acc[mq][nq]);               \
        acc[mq][nq] = MFMA32(af[mq][1], bfr[nq][1], acc[mq][nq]);               \
      }                                                                         \
    __builtin_amdgcn_s_setprio(0);                                              \
  }

  const int nk = K >> 5;  // 112
  STAGE_T(0, 0);
  STAGE_T(1, 1);
  if constexpr (CALLS == 4) asm volatile("s_waitcnt vmcnt(4)" ::: "memory");
  else                      asm volatile("s_waitcnt vmcnt(3)" ::: "memory");
  __builtin_amdgcn_s_barrier();

  for (int t = 0; t < nk - 2; ++t) {
    STAGE_T((t + 2) & 3, t + 2);
    KSTEP(t & 3);
    if constexpr (CALLS == 4) asm volatile("s_waitcnt vmcnt(4)" ::: "memory");
    else                      asm volatile("s_waitcnt vmcnt(3)" ::: "memory");
    __builtin_amdgcn_s_barrier();
  }
  for (int t = nk - 2; t < nk; ++t) {
    KSTEP(t & 3);
    asm volatile("s_waitcnt vmcnt(0)" ::: "memory");
    __builtin_amdgcn_s_barrier();
  }
#undef STAGE_T
#undef KSTEP

  // epilogue: 32x32 C/D layout col=lane&31, row=(reg&3)+8*(reg>>2)+4*(lane>>5)
#pragma unroll
  for (int mq = 0; mq < MQ; ++mq) {
#pragma unroll
    for (int nq = 0; nq < 2; ++nq) {
      const int col = tn + wn * 64 + nq * 32 + l31;
      const float bv = BIAS ? bias[col] : 0.0f;
#pragma unroll
      for (int reg = 0; reg < 16; ++reg) {
        const int row = tm + wm * (BM / 2) + mq * 32 + (reg & 3) + 8 * (reg >> 2) + 4 * g2;
        const float v = acc[mq][nq][reg] + bv;
        if (OUTBF) ((short*)outp)[(size_t)row * N + col] = f2bf(v);
        else       ((float*)outp)[(size_t)row * N + col] = v;
      }
    }
  }
}

// ---------------- flash attention, 2-phase pipelined, paired q-tiles --------
__global__ void __launch_bounds__(256) attn_kernel(const short* __restrict__ qkv,
                                                   const short* __restrict__ vtb,
                                                   short* __restrict__ outb) {
  const int lid = (int)blockIdx.x + ((int)blockIdx.y << 4);
  const int kvh = (lid & 7) >> 1;
  const int u = ((lid >> 3) << 1) + (lid & 1);  // 0..111 within kv group
  const int head = kvh * 7 + (u >> 4);
  const int qtA = u & 15, qtB = 31 - qtA;

  const int tid = threadIdx.x;
  const int lane = tid & 63, wave = tid >> 6;
  const int l15 = lane & 15, g = lane >> 4;

  __shared__ short Ks[2][64 * 128];
  __shared__ short Vs[2][128 * 64];
  __shared__ short Ps[4][16 * 64];

  const short* kbase = qkv + 3584 + kvh * 128;
  const short* vbase = vtb + (size_t)kvh * 128 * 2048;
  const float NINF = -__builtin_inff();

  bf16x8 qf[4];
  f32x4 o[8];
  float mrun[4], lrun[4];

#define LOADQ(qt)                                                                  \
  {                                                                                \
    const short* qptr =                                                            \
        qkv + (size_t)((qt)*64 + wave * 16 + l15) * 4608 + head * 128 + g * 8;     \
    _Pragma("unroll") for (int ds = 0; ds < 4; ++ds) qf[ds] =                      \
        *(const bf16x8*)(qptr + ds * 32);                                          \
  }
#define RESET()                                                                    \
  {                                                                                \
    _Pragma("unroll") for (int nd = 0; nd < 8; ++nd) o[nd] = f32x4{0.f,0.f,0.f,0.f}; \
    _Pragma("unroll") for (int r = 0; r < 4; ++r) { mrun[r] = NINF; lrun[r] = 0.f; } \
  }
#define STAGE(kv, b)                                                               \
  {                                                                                \
    _Pragma("unroll") for (int it = 0; it < 4; ++it) {                             \
      const int chunk = it * 256 + tid;                                            \
      const int row = chunk >> 4, sc = (chunk & 15) ^ (row & 7);                   \
      gll16(kbase + (size_t)((kv)*64 + row) * 4608 + sc * 8,                       \
            &Ks[b][(it * 256 + wave * 64) * 8]);                                   \
    }                                                                              \
    _Pragma("unroll") for (int it = 0; it < 4; ++it) {                             \
      const int chunk = it * 256 + tid;                                            \
      const int row = chunk >> 3, sc = (chunk & 7) ^ (row & 7);                    \
      gll16(vbase + (size_t)row * 2048 + (kv)*64 + sc * 8,                         \
            &Vs[b][(it * 256 + wave * 64) * 8]);                                   \
    }                                                                              \
  }

  RESET();
  LOADQ(qtA);
  STAGE(0, 0);
  __syncthreads();
  int cur = 0;

  for (int s = 0; s < 33; ++s) {
    if (s < 32) {
      const int sn = s + 1;
      const int kvn = (sn <= qtA) ? sn : sn - qtA - 1;
      STAGE(kvn, cur ^ 1);
    }
    const int qt = (s <= qtA) ? qtA : qtB;
    const int kv = (s <= qtA) ? s : s - qtA - 1;
    const bool diag = (s == qtA) || (s == 32);

    f32x4 sf[4] = {};
    __builtin_amdgcn_s_setprio(1);
#pragma unroll
    for (int n = 0; n < 4; ++n) {
      const int krow = n * 16 + l15;
#pragma unroll
      for (int ds = 0; ds < 4; ++ds) {
        const int c = (ds * 4 + g) ^ (krow & 7);
        const bf16x8 kf = *(const bf16x8*)(&Ks[cur][krow * 128 + c * 8]);
        sf[n] = MFMA16(qf[ds], kf, sf[n]);
      }
    }
    __builtin_amdgcn_s_setprio(0);

    if (diag) {
#pragma unroll
      for (int r = 0; r < 4; ++r) {
        const int qr = qt * 64 + wave * 16 + g * 4 + r;
#pragma unroll
        for (int n = 0; n < 4; ++n)
          if (kv * 64 + n * 16 + l15 > qr) sf[n][r] = NINF;
      }
    }
    float pmax[4];
#pragma unroll
    for (int r = 0; r < 4; ++r)
      pmax[r] = fmaxf(fmaxf(sf[0][r], sf[1][r]), fmaxf(sf[2][r], sf[3][r]));
    const bool need = (pmax[0] > mrun[0] + 8.f) || (pmax[1] > mrun[1] + 8.f) ||
                      (pmax[2] > mrun[2] + 8.f) || (pmax[3] > mrun[3] + 8.f);
    if (__any(need)) {
#pragma unroll
      for (int r = 0; r < 4; ++r) {
        float mx = pmax[r];
        mx = fmaxf(mx, __shfl_xor(mx, 1));
        mx = fmaxf(mx, __shfl_xor(mx, 2));
        mx = fmaxf(mx, __shfl_xor(mx, 4));
        mx = fmaxf(mx, __shfl_xor(mx, 8));
        const float mnew = fmaxf(mrun[r], mx);
        const float alpha = exp2f(mrun[r] - mnew);
        mrun[r] = mnew;
        lrun[r] *= alpha;
#pragma unroll
        for (int nd = 0; nd < 8; ++nd) o[nd][r] *= alpha;
      }
    }
#pragma unroll
    for (int n = 0; n < 4; ++n) {
#pragma unroll
      for (int r = 0; r < 4; ++r) {
        const float p = exp2f(sf[n][r] - mrun[r]);
        lrun[r] += p;
        const int prow = g * 4 + r, key = n * 16 + l15;
        const int cp = (key >> 3) ^ (prow & 7);
        Ps[wave][prow * 64 + cp * 8 + (key & 7)] = f2bf(p);
      }
    }
    bf16x8 pf[2];
#pragma unroll
    for (int ksl = 0; ksl < 2; ++ksl) {
      const int c = (ksl * 4 + g) ^ (l15 & 7);
      pf[ksl] = *(const bf16x8*)(&Ps[wave][l15 * 64 + c * 8]);
    }
    __builtin_amdgcn_s_setprio(1);
#pragma unroll
    for (int nd = 0; nd < 8; ++nd) {
      const int vrow = nd * 16 + l15;
#pragma unroll
      for (int ksl = 0; ksl < 2; ++ksl) {
        const int c = (ksl * 4 + g) ^ (vrow & 7);
        const bf16x8 vf = *(const bf16x8*)(&Vs[cur][vrow * 64 + c * 8]);
        o[nd] = MFMA16(pf[ksl], vf, o[nd]);
      }
    }
    __builtin_amdgcn_s_setprio(0);

    if (diag) {
      float inv[4];
#pragma unroll
      for (int r = 0; r < 4; ++r) {
        float sum = lrun[r];
        sum += __shfl_xor(sum, 1);
        sum += __shfl_xor(sum, 2);
        sum += __shfl_xor(sum, 4);
        sum += __shfl_xor(sum, 8);
        inv[r] = 1.0f / sum;
      }
#pragma unroll
      for (int nd = 0; nd < 8; ++nd) {
#pragma unroll
        for (int r = 0; r < 4; ++r) {
          const int qr = qt * 64 + wave * 16 + g * 4 + r;
          outb[(size_t)qr * 3584 + head * 128 + nd * 16 + l15] = f2bf(o[nd][r] * inv[r]);
        }
      }
      if (s == qtA) {
        RESET();
        LOADQ(qtB);
      }
    }
    __syncthreads();
    cur ^= 1;
  }
#undef LOADQ
#undef RESET
#undef STAGE
}

extern "C" void kernel_launch(void* const* d_in, const int* in_sizes, int n_in,
                              void* d_out, int out_size, void* d_ws, size_t ws_size,
                              hipStream_t stream) {
  const float* h  = (const float*)d_in[0];
  const int* pos  = (const int*)d_in[1];
  const float* Wq = (const float*)d_in[2];
  const float* bq = (const float*)d_in[3];
  const float* Wk = (const float*)d_in[4];
  const float* bk = (const float*)d_in[5];
  const float* Wv = (const float*)d_in[6];
  const float* bv = (const float*)d_in[7];
  const float* Wo = (const float*)d_in[8];
  float* out = (float*)d_out;

  char* w = (char*)d_ws;
  short* hbf  = (short*)w; w += (size_t)2048 * 3584 * 2;
  short* Wall = (short*)w; w += (size_t)4608 * 3584 * 2;
  float* ball = (float*)w; w += 4608 * 4;
  short* qkvp = (short*)w; w += (size_t)2048 * 4608 * 2;
  float* ctab = (float*)w; w += 2048 * 64 * 4;
  float* stab = (float*)w; w += 2048 * 64 * 4;
  short* vtb  = (short*)w; w += (size_t)4 * 128 * 2048 * 2;
  short* attnb = hbf;
  short* Wob = Wall;

  cvt_kernel<<<2048, 256, 0, stream>>>(h, hbf, (long long)2048 * 3584);
  cvt_kernel<<<2048, 256, 0, stream>>>(Wq, Wall, (long long)3584 * 3584);
  cvt_kernel<<<512, 256, 0, stream>>>(Wk, Wall + (size_t)3584 * 3584, (long long)512 * 3584);
  cvt_kernel<<<512, 256, 0, stream>>>(Wv, Wall + (size_t)4096 * 3584, (long long)512 * 3584);
  bias_concat<<<18, 256, 0, stream>>>(bq, bk, bv, ball);
  rope_table<<<2048, 64, 0, stream>>>(pos, ctab, stab);

  gemm32<256, true, true><<<144, 512, 0, stream>>>(hbf, Wall, ball, qkvp, 4608, 3584);
  rope_apply<<<2048, 256, 0, stream>>>(qkvp, ctab, stab);
  v_transpose<<<dim3(4, 32, 4), 256, 0, stream>>>(qkvp, vtb);
  cvt_kernel<<<2048, 256, 0, stream>>>(Wo, Wob, (long long)3584 * 3584);

  attn_kernel<<<dim3(16, 28), 256, 0, stream>>>(qkvp, vtb, attnb);

  gemm32<128, false, false><<<224, 512, 0, stream>>>(attnb, Wob, nullptr, out, 3584, 3584);
}

// Round 5
// 277.334 us; speedup vs baseline: 1.2103x; 1.0400x over previous
//
#include <hip/hip_runtime.h>

typedef __attribute__((ext_vector_type(4))) float f32x4;
typedef __attribute__((ext_vector_type(8))) short bf16x8;

#define MFMA16(a, b, c) __builtin_amdgcn_mfma_f32_16x16x32_bf16((a), (b), (c), 0, 0, 0)
#define LOG2E 1.44269504088896340736f

static __device__ __forceinline__ float bf2f(short u) {
  unsigned x = ((unsigned)(unsigned short)u) << 16;
  return __builtin_bit_cast(float, x);
}
static __device__ __forceinline__ short f2bf(float f) {
  unsigned u = __builtin_bit_cast(unsigned, f);
  u += 0x7fffu + ((u >> 16) & 1u);
  return (short)(u >> 16);
}
// global -> LDS direct DMA, 16B per lane. LDS dest is wave-uniform base +
// lane*16 (guide §5); swizzle done on the GLOBAL source address (rule #21).
static __device__ __forceinline__ void gll16(const void* g, void* l) {
  __builtin_amdgcn_global_load_lds(
      (const __attribute__((address_space(1))) unsigned*)(unsigned long long)g,
      (__attribute__((address_space(3))) unsigned*)(unsigned)(unsigned long long)l,
      16, 0, 0);
}

// ---------------- f32 -> bf16 conversion (vectorized, G13) ----------------
__global__ void __launch_bounds__(256) cvt_kernel(const float* __restrict__ src,
                                                  short* __restrict__ dst,
                                                  long long n) {
  long long i = ((long long)blockIdx.x * 256 + threadIdx.x) * 8;
  const long long stride = (long long)gridDim.x * 256 * 8;
  for (; i < n; i += stride) {
    f32x4 a = *(const f32x4*)(src + i);
    f32x4 b = *(const f32x4*)(src + i + 4);
    bf16x8 o;
    o[0] = f2bf(a[0]); o[1] = f2bf(a[1]); o[2] = f2bf(a[2]); o[3] = f2bf(a[3]);
    o[4] = f2bf(b[0]); o[5] = f2bf(b[1]); o[6] = f2bf(b[2]); o[7] = f2bf(b[3]);
    *(bf16x8*)(dst + i) = o;
  }
}

__global__ void bias_concat(const float* __restrict__ bq, const float* __restrict__ bk,
                            const float* __restrict__ bv, float* __restrict__ ball) {
  const int i = blockIdx.x * 256 + threadIdx.x;
  if (i < 3584) ball[i] = bq[i];
  else if (i < 4096) ball[i] = bk[i - 3584];
  else if (i < 4608) ball[i] = bv[i - 4096];
}

// ---------------- RoPE cos/sin table: [2048][64] ----------------
__global__ void rope_table(const int* __restrict__ pos, float* __restrict__ ctab,
                           float* __restrict__ stab) {
  const int s = blockIdx.x;
  const int i = threadIdx.x;  // 0..63
  const float p = (float)pos[s];
  const float ang = p * exp2f(-(float)i * 0.3114307588956902f);
  ctab[s * 64 + i] = cosf(ang);
  stab[s * 64 + i] = sinf(ang);
}

// In-place RoPE on q/k regions of qkv[2048][4608]. Q heads (h<28) are
// pre-scaled by SCALE*LOG2E so attention scores come out in exp2-domain.
__global__ void __launch_bounds__(256) rope_apply(short* __restrict__ qkv,
                                                  const float* __restrict__ ctab,
                                                  const float* __restrict__ stab) {
  const int idx = blockIdx.x * 256 + threadIdx.x;  // 2048*32*8
  const int c = idx & 7;
  const int h = (idx >> 3) & 31;
  const int s = idx >> 8;
  const float qs = (h < 28) ? (0.08838834764831845f * LOG2E) : 1.0f;
  short* base = qkv + (size_t)s * 4608 + h * 128 + c * 8;
  bf16x8 lo = *(bf16x8*)base;
  bf16x8 hi = *(bf16x8*)(base + 64);
  const float* cp = ctab + s * 64 + c * 8;
  const float* sp = stab + s * 64 + c * 8;
  bf16x8 lo2, hi2;
#pragma unroll
  for (int j = 0; j < 8; ++j) {
    const float x = bf2f(lo[j]), y = bf2f(hi[j]);
    const float cv = cp[j], sv = sp[j];
    lo2[j] = f2bf((x * cv - y * sv) * qs);
    hi2[j] = f2bf((y * cv + x * sv) * qs);
  }
  *(bf16x8*)base = lo2;
  *(bf16x8*)(base + 64) = hi2;
}

// V region of qkv -> V^T [4][128][2048]
__global__ void __launch_bounds__(256) v_transpose(const short* __restrict__ qkv,
                                                   short* __restrict__ vtb) {
  __shared__ short t[64 * 48];
  const int dt = blockIdx.x, st = blockIdx.y, kv = blockIdx.z;
  const int tid = threadIdx.x;
  {
    const int r = tid >> 2, c8 = tid & 3;
    const bf16x8 v = *(const bf16x8*)(qkv + (size_t)(st * 64 + r) * 4608 + 4096 +
                                      kv * 128 + dt * 32 + c8 * 8);
    *(bf16x8*)(t + r * 48 + c8 * 8) = v;
  }
  __syncthreads();
  {
    const int d = tid >> 3, c = tid & 7;
    bf16x8 v;
#pragma unroll
    for (int i = 0; i < 8; ++i) v[i] = t[(c * 8 + i) * 48 + d];
    *(bf16x8*)(vtb + ((size_t)kv * 128 + dt * 32 + d) * 2048 + st * 64 + c * 8) = v;
  }
}

// -------- 8-phase bf16 GEMM (faithful m201 port): BMx256 tile, BK=64 --------
// C[M=2048,N] = A[M,K]*B[N,K]^T (+bias). 8 waves (2M x 4N), per-wave BM/2 x 64.
// Quadrant order (rh,ch) = (0,0),(0,1),(1,1),(1,0): phase reads {12,4,8,0};
// af reloaded per A-half (disjoint liveness), b0 held P1..P4, b1 P2..P3.
// One half-tile stage (2 or 1 gll16 calls) per phase; each stage targets a
// half whose last LDS read was >=1 phase earlier (ledger-verified).
// vmcnt(W), W = ACH+2*BCH (3 half-tiles in flight) at P4/P8 only; vmcnt(0)
// only in the last iteration. LDS: linear dest, source-swizzled chunk
// (chunk ^ row&7) -> 2-way (free) ds_read_b128 (r2-verified, 0 conflicts).
// LDS row permutation groups rows by (half, wave): A ldsrow = h*BM/2 +
// wm*BM/4 + r (grow = wm*BM/2 + h*BM/4 + r); B ldsrow = h*128 + wn*32 + r
// (gcol = wn*64 + h*32 + r).
template <int BM, int NT, bool BIAS, bool OUTBF>
__global__ void __launch_bounds__(512, 2)
gemm8p(const short* __restrict__ A, const short* __restrict__ B,
       const float* __restrict__ bias, void* __restrict__ outp, int N, int K) {
  constexpr int MT = 2048 / BM;
  constexpr int MQ2 = BM / 64;       // m-frags per quadrant (256->4, 128->2)
  constexpr int ACH = BM / 128;      // gll16 calls per A half-tile
  constexpr int W = ACH + 4;         // vmcnt: 3 half-tiles in flight
  __shared__ short As[2][BM * 64];
  __shared__ short Bs[2][256 * 64];
  const int per = (int)gridDim.x >> 3;
  const int bid = (int)blockIdx.x;
  const int tile = (bid & 7) * per + (bid >> 3);  // bijective XCD swizzle
  const int tm = (tile / NT) * BM;
  const int tn = (tile % NT) * 256;
  const int tid = (int)threadIdx.x;
  const int wave = tid >> 6, lane = tid & 63;
  const int l15 = lane & 15, g = lane >> 4;
  const int wm = wave >> 2, wn = wave & 3;

  f32x4 acc[2][MQ2][2][2] = {};  // [rh][mq][ch][nq]
  bf16x8 af[MQ2][2], b0[2][2], b1[2][2];

#define STG_A(b, kt, h)                                                         \
  { _Pragma("unroll") for (int j = 0; j < ACH; ++j) {                           \
      const int lr = (h) * (BM / 2) + j * 64 + (tid >> 3);                      \
      const int wmm = (lr / (BM / 4)) & 1;                                      \
      const int rr = lr & (BM / 4 - 1);                                         \
      const int grow = wmm * (BM / 2) + (h) * (BM / 4) + rr;                    \
      const int sc = (tid & 7) ^ (rr & 7);                                      \
      gll16(A + (size_t)(tm + grow) * K + (size_t)(kt) * 64 + sc * 8,           \
            &As[b][((h) * (BM / 2) + j * 64 + wave * 8) * 64]);                 \
    } }
#define STG_B(b, kt, h)                                                         \
  { _Pragma("unroll") for (int j = 0; j < 2; ++j) {                             \
      const int lr = (h) * 128 + j * 64 + (tid >> 3);                           \
      const int wnn = (lr >> 5) & 3;                                            \
      const int rr = lr & 31;                                                   \
      const int gcol = wnn * 64 + (h) * 32 + rr;                                \
      const int sc = (tid & 7) ^ (rr & 7);                                      \
      gll16(B + (size_t)(tn + gcol) * K + (size_t)(kt) * 64 + sc * 8,           \
            &Bs[b][((h) * 128 + j * 64 + wave * 8) * 64]);                      \
    } }
#define LDA(buf, rh)                                                            \
  { _Pragma("unroll") for (int mq = 0; mq < MQ2; ++mq)                          \
      _Pragma("unroll") for (int ks = 0; ks < 2; ++ks) {                        \
        const int lr = (rh) * (BM / 2) + wm * (BM / 4) + mq * 16 + l15;         \
        af[mq][ks] =                                                            \
            *(const bf16x8*)(&As[buf][lr * 64 + (((ks * 4 + g) ^ (lr & 7)) * 8)]); \
      } }
#define LDB(buf, ch, ARR)                                                       \
  { _Pragma("unroll") for (int nq = 0; nq < 2; ++nq)                            \
      _Pragma("unroll") for (int ks = 0; ks < 2; ++ks) {                        \
        const int lr = (ch) * 128 + wn * 32 + nq * 16 + l15;                    \
        ARR[nq][ks] =                                                           \
            *(const bf16x8*)(&Bs[buf][lr * 64 + (((ks * 4 + g) ^ (lr & 7)) * 8)]); \
      } }
#define PH(RH, CH, BARR, LOADS, STAGES, WAITS)                                  \
  {                                                                             \
    LOADS;                                                                      \
    STAGES;                                                                     \
    __builtin_amdgcn_s_barrier();                                               \
    asm volatile("s_waitcnt lgkmcnt(0)" ::: "memory");                          \
    __builtin_amdgcn_sched_barrier(0);                                          \
    __builtin_amdgcn_s_setprio(1);                                              \
    _Pragma("unroll") for (int mq = 0; mq < MQ2; ++mq)                          \
      _Pragma("unroll") for (int nq = 0; nq < 2; ++nq) {                        \
        acc[RH][mq][CH][nq] = MFMA16(af[mq][0], BARR[nq][0], acc[RH][mq][CH][nq]); \
        acc[RH][mq][CH][nq] = MFMA16(af[mq][1], BARR[nq][1], acc[RH][mq][CH][nq]); \
      }                                                                         \
    __builtin_amdgcn_s_setprio(0);                                              \
    WAITS;                                                                      \
    __builtin_amdgcn_s_barrier();                                               \
  }
#define WAITW()                                                                 \
  { if constexpr (W == 6) { asm volatile("s_waitcnt vmcnt(6)" ::: "memory"); }  \
    else { asm volatile("s_waitcnt vmcnt(5)" ::: "memory"); } }

  // prologue: tile0 fully + 3 half-tiles of tile1 (A0,B0,B1)
  STG_A(0, 0, 0); STG_A(0, 0, 1); STG_B(0, 0, 0); STG_B(0, 0, 1);
  STG_A(1, 1, 0); STG_B(1, 1, 0); STG_B(1, 1, 1);
  WAITW();
  __builtin_amdgcn_s_barrier();

  const int L = K >> 7;  // 28 iterations, 2 K-tiles each
  for (int i = 0; i < L; ++i) {
    const int t1 = 2 * i + 1, t2 = 2 * i + 2, t3 = 2 * i + 3;
    const bool more = (i < L - 1);
    // P1: Q(0,0) buf0
    PH(0, 0, b0, { LDA(0, 0); LDB(0, 0, b0); }, { STG_A(1, t1, 1); }, {});
    // P2: Q(0,1) buf0
    PH(0, 1, b1, { LDB(0, 1, b1); }, { if (more) STG_A(0, t2, 0); }, {});
    // P3: Q(1,1) buf0
    PH(1, 1, b1, { LDA(0, 1); }, { if (more) STG_B(0, t2, 0); }, {});
    // P4: Q(1,0) buf0
    PH(1, 0, b0, {}, { if (more) STG_B(0, t2, 1); },
       { if (more) { WAITW(); } else { asm volatile("s_waitcnt vmcnt(0)" ::: "memory"); } });
    // P5: Q(0,0) buf1
    PH(0, 0, b0, { LDA(1, 0); LDB(1, 0, b0); }, { if (more) STG_A(0, t2, 1); }, {});
    // P6: Q(0,1) buf1
    PH(0, 1, b1, { LDB(1, 1, b1); }, { if (more) STG_A(1, t3, 0); }, {});
    // P7: Q(1,1) buf1
    PH(1, 1, b1, { LDA(1, 1); }, { if (more) STG_B(1, t3, 0); }, {});
    // P8: Q(1,0) buf1
    PH(1, 0, b0, {}, { if (more) STG_B(1, t3, 1); },
       { if (more) { WAITW(); } else { asm volatile("s_waitcnt vmcnt(0)" ::: "memory"); } });
  }
#undef STG_A
#undef STG_B
#undef LDA
#undef LDB
#undef PH
#undef WAITW

  // epilogue: 16x16 C/D layout col=lane&15, row=(lane>>4)*4+reg
#pragma unroll
  for (int rh = 0; rh < 2; ++rh)
#pragma unroll
    for (int mq = 0; mq < MQ2; ++mq)
#pragma unroll
      for (int ch = 0; ch < 2; ++ch)
#pragma unroll
        for (int nq = 0; nq < 2; ++nq) {
          const int col = tn + wn * 64 + ch * 32 + nq * 16 + l15;
          const float bv = BIAS ? bias[col] : 0.0f;
          const int row0 = tm + wm * (BM / 2) + rh * (BM / 4) + mq * 16 + g * 4;
#pragma unroll
          for (int r = 0; r < 4; ++r) {
            const float v = acc[rh][mq][ch][nq][r] + bv;
            if (OUTBF) ((short*)outp)[(size_t)(row0 + r) * N + col] = f2bf(v);
            else       ((float*)outp)[(size_t)(row0 + r) * N + col] = v;
          }
        }
}

// ---------------- flash attention, 2-phase pipelined, paired q-tiles --------
__global__ void __launch_bounds__(256) attn_kernel(const short* __restrict__ qkv,
                                                   const short* __restrict__ vtb,
                                                   short* __restrict__ outb) {
  const int lid = (int)blockIdx.x + ((int)blockIdx.y << 4);
  const int kvh = (lid & 7) >> 1;
  const int u = ((lid >> 3) << 1) + (lid & 1);  // 0..111 within kv group
  const int head = kvh * 7 + (u >> 4);
  const int qtA = u & 15, qtB = 31 - qtA;

  const int tid = threadIdx.x;
  const int lane = tid & 63, wave = tid >> 6;
  const int l15 = lane & 15, g = lane >> 4;

  __shared__ short Ks[2][64 * 128];
  __shared__ short Vs[2][128 * 64];
  __shared__ short Ps[4][16 * 64];

  const short* kbase = qkv + 3584 + kvh * 128;
  const short* vbase = vtb + (size_t)kvh * 128 * 2048;
  const float NINF = -__builtin_inff();

  bf16x8 qf[4];
  f32x4 o[8];
  float mrun[4], lrun[4];

#define LOADQ(qt)                                                                  \
  {                                                                                \
    const short* qptr =                                                            \
        qkv + (size_t)((qt)*64 + wave * 16 + l15) * 4608 + head * 128 + g * 8;     \
    _Pragma("unroll") for (int ds = 0; ds < 4; ++ds) qf[ds] =                      \
        *(const bf16x8*)(qptr + ds * 32);                                          \
  }
#define RESET()                                                                    \
  {                                                                                \
    _Pragma("unroll") for (int nd = 0; nd < 8; ++nd) o[nd] = f32x4{0.f,0.f,0.f,0.f}; \
    _Pragma("unroll") for (int r = 0; r < 4; ++r) { mrun[r] = NINF; lrun[r] = 0.f; } \
  }
#define STAGE(kv, b)                                                               \
  {                                                                                \
    _Pragma("unroll") for (int it = 0; it < 4; ++it) {                             \
      const int chunk = it * 256 + tid;                                            \
      const int row = chunk >> 4, sc = (chunk & 15) ^ (row & 7);                   \
      gll16(kbase + (size_t)((kv)*64 + row) * 4608 + sc * 8,                       \
            &Ks[b][(it * 256 + wave * 64) * 8]);                                   \
    }                                                                              \
    _Pragma("unroll") for (int it = 0; it < 4; ++it) {                             \
      const int chunk = it * 256 + tid;                                            \
      const int row = chunk >> 3, sc = (chunk & 7) ^ (row & 7);                    \
      gll16(vbase + (size_t)row * 2048 + (kv)*64 + sc * 8,                         \
            &Vs[b][(it * 256 + wave * 64) * 8]);                                   \
    }                                                                              \
  }

  RESET();
  LOADQ(qtA);
  STAGE(0, 0);
  __syncthreads();
  int cur = 0;

  for (int s = 0; s < 33; ++s) {
    if (s < 32) {
      const int sn = s + 1;
      const int kvn = (sn <= qtA) ? sn : sn - qtA - 1;
      STAGE(kvn, cur ^ 1);
    }
    const int qt = (s <= qtA) ? qtA : qtB;
    const int kv = (s <= qtA) ? s : s - qtA - 1;
    const bool diag = (s == qtA) || (s == 32);

    f32x4 sf[4] = {};
    __builtin_amdgcn_s_setprio(1);
#pragma unroll
    for (int n = 0; n < 4; ++n) {
      const int krow = n * 16 + l15;
#pragma unroll
      for (int ds = 0; ds < 4; ++ds) {
        const int c = (ds * 4 + g) ^ (krow & 7);
        const bf16x8 kf = *(const bf16x8*)(&Ks[cur][krow * 128 + c * 8]);
        sf[n] = MFMA16(qf[ds], kf, sf[n]);
      }
    }
    __builtin_amdgcn_s_setprio(0);

    if (diag) {
#pragma unroll
      for (int r = 0; r < 4; ++r) {
        const int qr = qt * 64 + wave * 16 + g * 4 + r;
#pragma unroll
        for (int n = 0; n < 4; ++n)
          if (kv * 64 + n * 16 + l15 > qr) sf[n][r] = NINF;
      }
    }
    float pmax[4];
#pragma unroll
    for (int r = 0; r < 4; ++r)
      pmax[r] = fmaxf(fmaxf(sf[0][r], sf[1][r]), fmaxf(sf[2][r], sf[3][r]));
    const bool need = (pmax[0] > mrun[0] + 8.f) || (pmax[1] > mrun[1] + 8.f) ||
                      (pmax[2] > mrun[2] + 8.f) || (pmax[3] > mrun[3] + 8.f);
    if (__any(need)) {
#pragma unroll
      for (int r = 0; r < 4; ++r) {
        float mx = pmax[r];
        mx = fmaxf(mx, __shfl_xor(mx, 1));
        mx = fmaxf(mx, __shfl_xor(mx, 2));
        mx = fmaxf(mx, __shfl_xor(mx, 4));
        mx = fmaxf(mx, __shfl_xor(mx, 8));
        const float mnew = fmaxf(mrun[r], mx);
        const float alpha = exp2f(mrun[r] - mnew);
        mrun[r] = mnew;
        lrun[r] *= alpha;
#pragma unroll
        for (int nd = 0; nd < 8; ++nd) o[nd][r] *= alpha;
      }
    }
#pragma unroll
    for (int n = 0; n < 4; ++n) {
#pragma unroll
      for (int r = 0; r < 4; ++r) {
        const float p = exp2f(sf[n][r] - mrun[r]);
        lrun[r] += p;
        const int prow = g * 4 + r, key = n * 16 + l15;
        const int cp = (key >> 3) ^ (prow & 7);
        Ps[wave][prow * 64 + cp * 8 + (key & 7)] = f2bf(p);
      }
    }
    bf16x8 pf[2];
#pragma unroll
    for (int ksl = 0; ksl < 2; ++ksl) {
      const int c = (ksl * 4 + g) ^ (l15 & 7);
      pf[ksl] = *(const bf16x8*)(&Ps[wave][l15 * 64 + c * 8]);
    }
    __builtin_amdgcn_s_setprio(1);
#pragma unroll
    for (int nd = 0; nd < 8; ++nd) {
      const int vrow = nd * 16 + l15;
#pragma unroll
      for (int ksl = 0; ksl < 2; ++ksl) {
        const int c = (ksl * 4 + g) ^ (vrow & 7);
        const bf16x8 vf = *(const bf16x8*)(&Vs[cur][vrow * 64 + c * 8]);
        o[nd] = MFMA16(pf[ksl], vf, o[nd]);
      }
    }
    __builtin_amdgcn_s_setprio(0);

    if (diag) {
      float inv[4];
#pragma unroll
      for (int r = 0; r < 4; ++r) {
        float sum = lrun[r];
        sum += __shfl_xor(sum, 1);
        sum += __shfl_xor(sum, 2);
        sum += __shfl_xor(sum, 4);
        sum += __shfl_xor(sum, 8);
        inv[r] = 1.0f / sum;
      }
#pragma unroll
      for (int nd = 0; nd < 8; ++nd) {
#pragma unroll
        for (int r = 0; r < 4; ++r) {
          const int qr = qt * 64 + wave * 16 + g * 4 + r;
          outb[(size_t)qr * 3584 + head * 128 + nd * 16 + l15] = f2bf(o[nd][r] * inv[r]);
        }
      }
      if (s == qtA) {
        RESET();
        LOADQ(qtB);
      }
    }
    __syncthreads();
    cur ^= 1;
  }
#undef LOADQ
#undef RESET
#undef STAGE
}

extern "C" void kernel_launch(void* const* d_in, const int* in_sizes, int n_in,
                              void* d_out, int out_size, void* d_ws, size_t ws_size,
                              hipStream_t stream) {
  const float* h  = (const float*)d_in[0];
  const int* pos  = (const int*)d_in[1];
  const float* Wq = (const float*)d_in[2];
  const float* bq = (const float*)d_in[3];
  const float* Wk = (const float*)d_in[4];
  const float* bk = (const float*)d_in[5];
  const float* Wv = (const float*)d_in[6];
  const float* bv = (const float*)d_in[7];
  const float* Wo = (const float*)d_in[8];
  float* out = (float*)d_out;

  char* w = (char*)d_ws;
  short* hbf  = (short*)w; w += (size_t)2048 * 3584 * 2;
  short* Wall = (short*)w; w += (size_t)4608 * 3584 * 2;
  float* ball = (float*)w; w += 4608 * 4;
  short* qkvp = (short*)w; w += (size_t)2048 * 4608 * 2;
  float* ctab = (float*)w; w += 2048 * 64 * 4;
  float* stab = (float*)w; w += 2048 * 64 * 4;
  short* vtb  = (short*)w; w += (size_t)4 * 128 * 2048 * 2;
  short* attnb = hbf;
  short* Wob = Wall;

  cvt_kernel<<<2048, 256, 0, stream>>>(h, hbf, (long long)2048 * 3584);
  cvt_kernel<<<2048, 256, 0, stream>>>(Wq, Wall, (long long)3584 * 3584);
  cvt_kernel<<<512, 256, 0, stream>>>(Wk, Wall + (size_t)3584 * 3584, (long long)512 * 3584);
  cvt_kernel<<<512, 256, 0, stream>>>(Wv, Wall + (size_t)4096 * 3584, (long long)512 * 3584);
  bias_concat<<<18, 256, 0, stream>>>(bq, bk, bv, ball);
  rope_table<<<2048, 64, 0, stream>>>(pos, ctab, stab);

  gemm8p<256, 18, true, true><<<144, 512, 0, stream>>>(hbf, Wall, ball, qkvp, 4608, 3584);
  rope_apply<<<2048, 256, 0, stream>>>(qkvp, ctab, stab);
  v_transpose<<<dim3(4, 32, 4), 256, 0, stream>>>(qkvp, vtb);
  cvt_kernel<<<2048, 256, 0, stream>>>(Wo, Wob, (long long)3584 * 3584);

  attn_kernel<<<dim3(16, 28), 256, 0, stream>>>(qkvp, vtb, attnb);

  gemm8p<128, 14, false, false><<<224, 512, 0, stream>>>(attnb, Wob, nullptr, out, 3584, 3584);
}

// Round 6
// 261.279 us; speedup vs baseline: 1.2847x; 1.0614x over previous
//
#include <hip/hip_runtime.h>

typedef __attribute__((ext_vector_type(4))) float f32x4;
typedef __attribute__((ext_vector_type(8))) short bf16x8;

#define MFMA16(a, b, c) __builtin_amdgcn_mfma_f32_16x16x32_bf16((a), (b), (c), 0, 0, 0)
#define LOG2E 1.44269504088896340736f

static __device__ __forceinline__ float bf2f(short u) {
  unsigned x = ((unsigned)(unsigned short)u) << 16;
  return __builtin_bit_cast(float, x);
}
static __device__ __forceinline__ short f2bf(float f) {
  unsigned u = __builtin_bit_cast(unsigned, f);
  u += 0x7fffu + ((u >> 16) & 1u);
  return (short)(u >> 16);
}
// global -> LDS direct DMA, 16B per lane. LDS dest is wave-uniform base +
// lane*16 (guide §5); swizzle done on the GLOBAL source address (rule #21).
static __device__ __forceinline__ void gll16(const void* g, void* l) {
  __builtin_amdgcn_global_load_lds(
      (const __attribute__((address_space(1))) unsigned*)(unsigned long long)g,
      (__attribute__((address_space(3))) unsigned*)(unsigned)(unsigned long long)l,
      16, 0, 0);
}

// ---------------- f32 -> bf16 conversion (vectorized, G13) ----------------
__global__ void __launch_bounds__(256) cvt_kernel(const float* __restrict__ src,
                                                  short* __restrict__ dst,
                                                  long long n) {
  long long i = ((long long)blockIdx.x * 256 + threadIdx.x) * 8;
  const long long stride = (long long)gridDim.x * 256 * 8;
  for (; i < n; i += stride) {
    f32x4 a = *(const f32x4*)(src + i);
    f32x4 b = *(const f32x4*)(src + i + 4);
    bf16x8 o;
    o[0] = f2bf(a[0]); o[1] = f2bf(a[1]); o[2] = f2bf(a[2]); o[3] = f2bf(a[3]);
    o[4] = f2bf(b[0]); o[5] = f2bf(b[1]); o[6] = f2bf(b[2]); o[7] = f2bf(b[3]);
    *(bf16x8*)(dst + i) = o;
  }
}

__global__ void bias_concat(const float* __restrict__ bq, const float* __restrict__ bk,
                            const float* __restrict__ bv, float* __restrict__ ball) {
  const int i = blockIdx.x * 256 + threadIdx.x;
  if (i < 3584) ball[i] = bq[i];
  else if (i < 4096) ball[i] = bk[i - 3584];
  else if (i < 4608) ball[i] = bv[i - 4096];
}

// ---------------- RoPE cos/sin table: [2048][64] ----------------
__global__ void rope_table(const int* __restrict__ pos, float* __restrict__ ctab,
                           float* __restrict__ stab) {
  const int s = blockIdx.x;
  const int i = threadIdx.x;  // 0..63
  const float p = (float)pos[s];
  const float ang = p * exp2f(-(float)i * 0.3114307588956902f);
  ctab[s * 64 + i] = cosf(ang);
  stab[s * 64 + i] = sinf(ang);
}

// In-place RoPE on q/k regions of qkv[2048][4608]. Q heads (h<28) are
// pre-scaled by SCALE*LOG2E so attention scores come out in exp2-domain.
__global__ void __launch_bounds__(256) rope_apply(short* __restrict__ qkv,
                                                  const float* __restrict__ ctab,
                                                  const float* __restrict__ stab) {
  const int idx = blockIdx.x * 256 + threadIdx.x;  // 2048*32*8
  const int c = idx & 7;
  const int h = (idx >> 3) & 31;
  const int s = idx >> 8;
  const float qs = (h < 28) ? (0.08838834764831845f * LOG2E) : 1.0f;
  short* base = qkv + (size_t)s * 4608 + h * 128 + c * 8;
  bf16x8 lo = *(bf16x8*)base;
  bf16x8 hi = *(bf16x8*)(base + 64);
  const float* cp = ctab + s * 64 + c * 8;
  const float* sp = stab + s * 64 + c * 8;
  bf16x8 lo2, hi2;
#pragma unroll
  for (int j = 0; j < 8; ++j) {
    const float x = bf2f(lo[j]), y = bf2f(hi[j]);
    const float cv = cp[j], sv = sp[j];
    lo2[j] = f2bf((x * cv - y * sv) * qs);
    hi2[j] = f2bf((y * cv + x * sv) * qs);
  }
  *(bf16x8*)base = lo2;
  *(bf16x8*)(base + 64) = hi2;
}

// V region of qkv -> V^T [4][128][2048]
__global__ void __launch_bounds__(256) v_transpose(const short* __restrict__ qkv,
                                                   short* __restrict__ vtb) {
  __shared__ short t[64 * 48];
  const int dt = blockIdx.x, st = blockIdx.y, kv = blockIdx.z;
  const int tid = threadIdx.x;
  {
    const int r = tid >> 2, c8 = tid & 3;
    const bf16x8 v = *(const bf16x8*)(qkv + (size_t)(st * 64 + r) * 4608 + 4096 +
                                      kv * 128 + dt * 32 + c8 * 8);
    *(bf16x8*)(t + r * 48 + c8 * 8) = v;
  }
  __syncthreads();
  {
    const int d = tid >> 3, c = tid & 7;
    bf16x8 v;
#pragma unroll
    for (int i = 0; i < 8; ++i) v[i] = t[(c * 8 + i) * 48 + d];
    *(bf16x8*)(vtb + ((size_t)kv * 128 + dt * 32 + d) * 2048 + st * 64 + c * 8) = v;
  }
}

// ------ 8-phase bf16 GEMM, ONE barrier per phase, race-free ledger ---------
// C[M=2048,N] = A[M,K]*B[N,K]^T (+bias). BMx256 tile, 8 waves (2M x 4N),
// BK=64, 2 K-tiles/iter double-buffered. Per phase: {bar; RD(own frags);
// lgkmcnt(0); sched_barrier; MFMA setprio'd; STG; [vmcnt(W) @P4/P8]}.
// Ledger (construction-race-free): every STG targets a region whose last
// ds_read was in a STRICTLY EARLIER phase (reader retired before stager
// passed this phase's barrier); every RD of new data is covered by a vmcnt
// (P8's covers P2-P4 stages for next P1-P3; P4's covers prev P6-P8 for
// P5-P7) followed by a barrier. W = 2*ACH+4. Never vmcnt(0) in main loop.
// 2D XCD chunking: xcd=bid%8 owns an MCHxNCH tile rectangle.
template <int BM, int NT, int MCH, int NCH, bool BIAS, bool OUTBF>
__global__ void __launch_bounds__(512, 2)
gemm9(const short* __restrict__ A, const short* __restrict__ B,
      const float* __restrict__ bias, void* __restrict__ outp, int N, int K) {
  constexpr int MQ2 = BM / 64;     // m-frags per rh-half (256->4, 128->2)
  constexpr int ACH = BM / 128;    // gll16 calls per A half-tile
  constexpr int W = 2 * ACH + 4;   // counted vmcnt
  __shared__ short As[2][BM * 64];
  __shared__ short Bs[2][256 * 64];
  const int bid = (int)blockIdx.x;
  const int xcd = bid & 7, idx = bid >> 3;
  const int rowg = xcd / (NT / NCH), colg = xcd % (NT / NCH);
  const int tm = (rowg * MCH + idx % MCH) * BM;
  const int tn = (colg * NCH + idx / MCH) * 256;
  const int tid = (int)threadIdx.x;
  const int wave = tid >> 6, lane = tid & 63;
  const int l15 = lane & 15, g = lane >> 4;
  const int wm = wave >> 2, wn = wave & 3;

  f32x4 acc[2][MQ2][2][2] = {};  // [rh][mq][ch][nq]
  bf16x8 af[MQ2][2], b0[2][2], b1[2][2];

#define STG_A(b, kt, h)                                                         \
  { _Pragma("unroll") for (int j = 0; j < ACH; ++j) {                           \
      const int lr = (h) * (BM / 2) + j * 64 + (tid >> 3);                      \
      const int wmm = (lr / (BM / 4)) & 1;                                      \
      const int rr = lr & (BM / 4 - 1);                                         \
      const int grow = wmm * (BM / 2) + (h) * (BM / 4) + rr;                    \
      const int sc = (tid & 7) ^ (rr & 7);                                      \
      gll16(A + (size_t)(tm + grow) * K + (size_t)(kt) * 64 + sc * 8,           \
            &As[b][((h) * (BM / 2) + j * 64 + wave * 8) * 64]);                 \
    } }
#define STG_B(b, kt, h)                                                         \
  { _Pragma("unroll") for (int j = 0; j < 2; ++j) {                             \
      const int lr = (h) * 128 + j * 64 + (tid >> 3);                           \
      const int wnn = (lr >> 5) & 3;                                            \
      const int rr = lr & 31;                                                   \
      const int gcol = wnn * 64 + (h) * 32 + rr;                                \
      const int sc = (tid & 7) ^ (rr & 7);                                      \
      gll16(B + (size_t)(tn + gcol) * K + (size_t)(kt) * 64 + sc * 8,           \
            &Bs[b][((h) * 128 + j * 64 + wave * 8) * 64]);                      \
    } }
#define LDA(buf, rh)                                                            \
  { _Pragma("unroll") for (int mq = 0; mq < MQ2; ++mq)                          \
      _Pragma("unroll") for (int ks = 0; ks < 2; ++ks) {                        \
        const int lr = (rh) * (BM / 2) + wm * (BM / 4) + mq * 16 + l15;         \
        af[mq][ks] =                                                            \
            *(const bf16x8*)(&As[buf][lr * 64 + (((ks * 4 + g) ^ (lr & 7)) * 8)]); \
      } }
#define LDB(buf, ch, ARR)                                                       \
  { _Pragma("unroll") for (int nq = 0; nq < 2; ++nq)                            \
      _Pragma("unroll") for (int ks = 0; ks < 2; ++ks) {                        \
        const int lr = (ch) * 128 + wn * 32 + nq * 16 + l15;                    \
        ARR[nq][ks] =                                                           \
            *(const bf16x8*)(&Bs[buf][lr * 64 + (((ks * 4 + g) ^ (lr & 7)) * 8)]); \
      } }
#define VMW()                                                                   \
  { if constexpr (W == 8) { asm volatile("s_waitcnt vmcnt(8)" ::: "memory"); }  \
    else { asm volatile("s_waitcnt vmcnt(6)" ::: "memory"); } }
#define PH(RH, CH, BARR, RDBLK, TAILBLK)                                        \
  {                                                                             \
    __builtin_amdgcn_s_barrier();                                               \
    RDBLK;                                                                      \
    asm volatile("s_waitcnt lgkmcnt(0)" ::: "memory");                          \
    __builtin_amdgcn_sched_barrier(0);                                          \
    __builtin_amdgcn_s_setprio(1);                                              \
    _Pragma("unroll") for (int mq = 0; mq < MQ2; ++mq)                          \
      _Pragma("unroll") for (int nq = 0; nq < 2; ++nq) {                        \
        acc[RH][mq][CH][nq] = MFMA16(af[mq][0], BARR[nq][0], acc[RH][mq][CH][nq]); \
        acc[RH][mq][CH][nq] = MFMA16(af[mq][1], BARR[nq][1], acc[RH][mq][CH][nq]); \
      }                                                                         \
    __builtin_amdgcn_s_setprio(0);                                              \
    TAILBLK;                                                                    \
  }

  // prologue: stage t0 (buf0) then t1 (buf1); vmcnt(W) leaves t1's W calls
  STG_A(0, 0, 0); STG_A(0, 0, 1); STG_B(0, 0, 0); STG_B(0, 0, 1);
  STG_A(1, 1, 0); STG_A(1, 1, 1); STG_B(1, 1, 0); STG_B(1, 1, 1);
  VMW();

  const int L = K >> 7;  // 28 iterations, 2 K-tiles each
  for (int i = 0; i < L; ++i) {
    const int t2 = 2 * i + 2, t3 = 2 * i + 3;
    const bool more = (i < L - 1);
    PH(0, 0, b0, { LDA(0, 0); LDB(0, 0, b0); }, {});
    PH(0, 1, b1, { LDB(0, 1, b1); }, { if (more) STG_A(0, t2, 0); });
    PH(1, 1, b1, { LDA(0, 1); }, { if (more) STG_B(0, t2, 1); });
    PH(1, 0, b0, {},
       { if (more) { STG_A(0, t2, 1); STG_B(0, t2, 0); VMW(); }
         else { asm volatile("s_waitcnt vmcnt(0)" ::: "memory"); } });
    PH(0, 0, b0, { LDA(1, 0); LDB(1, 0, b0); }, {});
    PH(0, 1, b1, { LDB(1, 1, b1); }, { if (more) STG_A(1, t3, 0); });
    PH(1, 1, b1, { LDA(1, 1); }, { if (more) STG_B(1, t3, 1); });
    PH(1, 0, b0, {},
       { if (more) { STG_A(1, t3, 1); STG_B(1, t3, 0); VMW(); } });
  }
#undef STG_A
#undef STG_B
#undef LDA
#undef LDB
#undef VMW
#undef PH

  // epilogue: 16x16 C/D layout col=lane&15, row=(lane>>4)*4+reg
#pragma unroll
  for (int rh = 0; rh < 2; ++rh)
#pragma unroll
    for (int mq = 0; mq < MQ2; ++mq)
#pragma unroll
      for (int ch = 0; ch < 2; ++ch)
#pragma unroll
        for (int nq = 0; nq < 2; ++nq) {
          const int col = tn + wn * 64 + ch * 32 + nq * 16 + l15;
          const float bv = BIAS ? bias[col] : 0.0f;
          const int row0 = tm + wm * (BM / 2) + rh * (BM / 4) + mq * 16 + g * 4;
#pragma unroll
          for (int r = 0; r < 4; ++r) {
            const float v = acc[rh][mq][ch][nq][r] + bv;
            if (OUTBF) ((short*)outp)[(size_t)(row0 + r) * N + col] = f2bf(v);
            else       ((float*)outp)[(size_t)(row0 + r) * N + col] = v;
          }
        }
}

// ---------------- flash attention, 2-phase pipelined, paired q-tiles --------
__global__ void __launch_bounds__(256) attn_kernel(const short* __restrict__ qkv,
                                                   const short* __restrict__ vtb,
                                                   short* __restrict__ outb) {
  const int lid = (int)blockIdx.x + ((int)blockIdx.y << 4);
  const int kvh = (lid & 7) >> 1;
  const int u = ((lid >> 3) << 1) + (lid & 1);  // 0..111 within kv group
  const int head = kvh * 7 + (u >> 4);
  const int qtA = u & 15, qtB = 31 - qtA;

  const int tid = threadIdx.x;
  const int lane = tid & 63, wave = tid >> 6;
  const int l15 = lane & 15, g = lane >> 4;

  __shared__ short Ks[2][64 * 128];
  __shared__ short Vs[2][128 * 64];
  __shared__ short Ps[4][16 * 64];

  const short* kbase = qkv + 3584 + kvh * 128;
  const short* vbase = vtb + (size_t)kvh * 128 * 2048;
  const float NINF = -__builtin_inff();

  bf16x8 qf[4];
  f32x4 o[8];
  float mrun[4], lrun[4];

#define LOADQ(qt)                                                                  \
  {                                                                                \
    const short* qptr =                                                            \
        qkv + (size_t)((qt)*64 + wave * 16 + l15) * 4608 + head * 128 + g * 8;     \
    _Pragma("unroll") for (int ds = 0; ds < 4; ++ds) qf[ds] =                      \
        *(const bf16x8*)(qptr + ds * 32);                                          \
  }
#define RESET()                                                                    \
  {                                                                                \
    _Pragma("unroll") for (int nd = 0; nd < 8; ++nd) o[nd] = f32x4{0.f,0.f,0.f,0.f}; \
    _Pragma("unroll") for (int r = 0; r < 4; ++r) { mrun[r] = NINF; lrun[r] = 0.f; } \
  }
#define STAGE(kv, b)                                                               \
  {                                                                                \
    _Pragma("unroll") for (int it = 0; it < 4; ++it) {                             \
      const int chunk = it * 256 + tid;                                            \
      const int row = chunk >> 4, sc = (chunk & 15) ^ (row & 7);                   \
      gll16(kbase + (size_t)((kv)*64 + row) * 4608 + sc * 8,                       \
            &Ks[b][(it * 256 + wave * 64) * 8]);                                   \
    }                                                                              \
    _Pragma("unroll") for (int it = 0; it < 4; ++it) {                             \
      const int chunk = it * 256 + tid;                                            \
      const int row = chunk >> 3, sc = (chunk & 7) ^ (row & 7);                    \
      gll16(vbase + (size_t)row * 2048 + (kv)*64 + sc * 8,                         \
            &Vs[b][(it * 256 + wave * 64) * 8]);                                   \
    }                                                                              \
  }

  RESET();
  LOADQ(qtA);
  STAGE(0, 0);
  __syncthreads();
  int cur = 0;

  for (int s = 0; s < 33; ++s) {
    if (s < 32) {
      const int sn = s + 1;
      const int kvn = (sn <= qtA) ? sn : sn - qtA - 1;
      STAGE(kvn, cur ^ 1);
    }
    const int qt = (s <= qtA) ? qtA : qtB;
    const int kv = (s <= qtA) ? s : s - qtA - 1;
    const bool diag = (s == qtA) || (s == 32);

    f32x4 sf[4] = {};
    __builtin_amdgcn_s_setprio(1);
#pragma unroll
    for (int n = 0; n < 4; ++n) {
      const int krow = n * 16 + l15;
#pragma unroll
      for (int ds = 0; ds < 4; ++ds) {
        const int c = (ds * 4 + g) ^ (krow & 7);
        const bf16x8 kf = *(const bf16x8*)(&Ks[cur][krow * 128 + c * 8]);
        sf[n] = MFMA16(qf[ds], kf, sf[n]);
      }
    }
    __builtin_amdgcn_s_setprio(0);

    if (diag) {
#pragma unroll
      for (int r = 0; r < 4; ++r) {
        const int qr = qt * 64 + wave * 16 + g * 4 + r;
#pragma unroll
        for (int n = 0; n < 4; ++n)
          if (kv * 64 + n * 16 + l15 > qr) sf[n][r] = NINF;
      }
    }
    float pmax[4];
#pragma unroll
    for (int r = 0; r < 4; ++r)
      pmax[r] = fmaxf(fmaxf(sf[0][r], sf[1][r]), fmaxf(sf[2][r], sf[3][r]));
    const bool need = (pmax[0] > mrun[0] + 8.f) || (pmax[1] > mrun[1] + 8.f) ||
                      (pmax[2] > mrun[2] + 8.f) || (pmax[3] > mrun[3] + 8.f);
    if (__any(need)) {
#pragma unroll
      for (int r = 0; r < 4; ++r) {
        float mx = pmax[r];
        mx = fmaxf(mx, __shfl_xor(mx, 1));
        mx = fmaxf(mx, __shfl_xor(mx, 2));
        mx = fmaxf(mx, __shfl_xor(mx, 4));
        mx = fmaxf(mx, __shfl_xor(mx, 8));
        const float mnew = fmaxf(mrun[r], mx);
        const float alpha = exp2f(mrun[r] - mnew);
        mrun[r] = mnew;
        lrun[r] *= alpha;
#pragma unroll
        for (int nd = 0; nd < 8; ++nd) o[nd][r] *= alpha;
      }
    }
#pragma unroll
    for (int n = 0; n < 4; ++n) {
#pragma unroll
      for (int r = 0; r < 4; ++r) {
        const float p = exp2f(sf[n][r] - mrun[r]);
        lrun[r] += p;
        const int prow = g * 4 + r, key = n * 16 + l15;
        const int cp = (key >> 3) ^ (prow & 7);
        Ps[wave][prow * 64 + cp * 8 + (key & 7)] = f2bf(p);
      }
    }
    bf16x8 pf[2];
#pragma unroll
    for (int ksl = 0; ksl < 2; ++ksl) {
      const int c = (ksl * 4 + g) ^ (l15 & 7);
      pf[ksl] = *(const bf16x8*)(&Ps[wave][l15 * 64 + c * 8]);
    }
    __builtin_amdgcn_s_setprio(1);
#pragma unroll
    for (int nd = 0; nd < 8; ++nd) {
      const int vrow = nd * 16 + l15;
#pragma unroll
      for (int ksl = 0; ksl < 2; ++ksl) {
        const int c = (ksl * 4 + g) ^ (vrow & 7);
        const bf16x8 vf = *(const bf16x8*)(&Vs[cur][vrow * 64 + c * 8]);
        o[nd] = MFMA16(pf[ksl], vf, o[nd]);
      }
    }
    __builtin_amdgcn_s_setprio(0);

    if (diag) {
      float inv[4];
#pragma unroll
      for (int r = 0; r < 4; ++r) {
        float sum = lrun[r];
        sum += __shfl_xor(sum, 1);
        sum += __shfl_xor(sum, 2);
        sum += __shfl_xor(sum, 4);
        sum += __shfl_xor(sum, 8);
        inv[r] = 1.0f / sum;
      }
#pragma unroll
      for (int nd = 0; nd < 8; ++nd) {
#pragma unroll
        for (int r = 0; r < 4; ++r) {
          const int qr = qt * 64 + wave * 16 + g * 4 + r;
          outb[(size_t)qr * 3584 + head * 128 + nd * 16 + l15] = f2bf(o[nd][r] * inv[r]);
        }
      }
      if (s == qtA) {
        RESET();
        LOADQ(qtB);
      }
    }
    __syncthreads();
    cur ^= 1;
  }
#undef LOADQ
#undef RESET
#undef STAGE
}

extern "C" void kernel_launch(void* const* d_in, const int* in_sizes, int n_in,
                              void* d_out, int out_size, void* d_ws, size_t ws_size,
                              hipStream_t stream) {
  const float* h  = (const float*)d_in[0];
  const int* pos  = (const int*)d_in[1];
  const float* Wq = (const float*)d_in[2];
  const float* bq = (const float*)d_in[3];
  const float* Wk = (const float*)d_in[4];
  const float* bk = (const float*)d_in[5];
  const float* Wv = (const float*)d_in[6];
  const float* bv = (const float*)d_in[7];
  const float* Wo = (const float*)d_in[8];
  float* out = (float*)d_out;

  char* w = (char*)d_ws;
  short* hbf  = (short*)w; w += (size_t)2048 * 3584 * 2;
  short* Wall = (short*)w; w += (size_t)4608 * 3584 * 2;
  float* ball = (float*)w; w += 4608 * 4;
  short* qkvp = (short*)w; w += (size_t)2048 * 4608 * 2;
  float* ctab = (float*)w; w += 2048 * 64 * 4;
  float* stab = (float*)w; w += 2048 * 64 * 4;
  short* vtb  = (short*)w; w += (size_t)4 * 128 * 2048 * 2;
  short* attnb = hbf;
  short* Wob = Wall;

  cvt_kernel<<<2048, 256, 0, stream>>>(h, hbf, (long long)2048 * 3584);
  cvt_kernel<<<2048, 256, 0, stream>>>(Wq, Wall, (long long)3584 * 3584);
  cvt_kernel<<<512, 256, 0, stream>>>(Wk, Wall + (size_t)3584 * 3584, (long long)512 * 3584);
  cvt_kernel<<<512, 256, 0, stream>>>(Wv, Wall + (size_t)4096 * 3584, (long long)512 * 3584);
  bias_concat<<<18, 256, 0, stream>>>(bq, bk, bv, ball);
  rope_table<<<2048, 64, 0, stream>>>(pos, ctab, stab);

  gemm9<256, 18, 2, 9, true, true><<<144, 512, 0, stream>>>(hbf, Wall, ball, qkvp, 4608, 3584);
  rope_apply<<<2048, 256, 0, stream>>>(qkvp, ctab, stab);
  v_transpose<<<dim3(4, 32, 4), 256, 0, stream>>>(qkvp, vtb);
  cvt_kernel<<<2048, 256, 0, stream>>>(Wo, Wob, (long long)3584 * 3584);

  attn_kernel<<<dim3(16, 28), 256, 0, stream>>>(qkvp, vtb, attnb);

  gemm9<128, 14, 4, 7, false, false><<<224, 512, 0, stream>>>(attnb, Wob, nullptr, out, 3584, 3584);
}

// Round 7
// 249.604 us; speedup vs baseline: 1.3448x; 1.0468x over previous
//
#include <hip/hip_runtime.h>

typedef __attribute__((ext_vector_type(4))) float f32x4;
typedef __attribute__((ext_vector_type(8))) short bf16x8;

#define MFMA16(a, b, c) __builtin_amdgcn_mfma_f32_16x16x32_bf16((a), (b), (c), 0, 0, 0)
#define LOG2E 1.44269504088896340736f

static __device__ __forceinline__ float bf2f(short u) {
  unsigned x = ((unsigned)(unsigned short)u) << 16;
  return __builtin_bit_cast(float, x);
}
static __device__ __forceinline__ short f2bf(float f) {
  unsigned u = __builtin_bit_cast(unsigned, f);
  u += 0x7fffu + ((u >> 16) & 1u);
  return (short)(u >> 16);
}
// global -> LDS direct DMA, 16B per lane. LDS dest is wave-uniform base +
// lane*16 (guide §5); swizzle done on the GLOBAL source address (rule #21).
static __device__ __forceinline__ void gll16(const void* g, void* l) {
  __builtin_amdgcn_global_load_lds(
      (const __attribute__((address_space(1))) unsigned*)(unsigned long long)g,
      (__attribute__((address_space(3))) unsigned*)(unsigned)(unsigned long long)l,
      16, 0, 0);
}

// ---------------- f32 -> bf16 conversion (vectorized, G13) ----------------
__global__ void __launch_bounds__(256) cvt_kernel(const float* __restrict__ src,
                                                  short* __restrict__ dst,
                                                  long long n) {
  long long i = ((long long)blockIdx.x * 256 + threadIdx.x) * 8;
  const long long stride = (long long)gridDim.x * 256 * 8;
  for (; i < n; i += stride) {
    f32x4 a = *(const f32x4*)(src + i);
    f32x4 b = *(const f32x4*)(src + i + 4);
    bf16x8 o;
    o[0] = f2bf(a[0]); o[1] = f2bf(a[1]); o[2] = f2bf(a[2]); o[3] = f2bf(a[3]);
    o[4] = f2bf(b[0]); o[5] = f2bf(b[1]); o[6] = f2bf(b[2]); o[7] = f2bf(b[3]);
    *(bf16x8*)(dst + i) = o;
  }
}

__global__ void bias_concat(const float* __restrict__ bq, const float* __restrict__ bk,
                            const float* __restrict__ bv, float* __restrict__ ball) {
  const int i = blockIdx.x * 256 + threadIdx.x;
  if (i < 3584) ball[i] = bq[i];
  else if (i < 4096) ball[i] = bk[i - 3584];
  else if (i < 4608) ball[i] = bv[i - 4096];
}

// ---------------- RoPE cos/sin table: [2048][64] ----------------
__global__ void rope_table(const int* __restrict__ pos, float* __restrict__ ctab,
                           float* __restrict__ stab) {
  const int s = blockIdx.x;
  const int i = threadIdx.x;  // 0..63
  const float p = (float)pos[s];
  const float ang = p * exp2f(-(float)i * 0.3114307588956902f);
  ctab[s * 64 + i] = cosf(ang);
  stab[s * 64 + i] = sinf(ang);
}

// In-place RoPE on q/k regions of qkv[2048][4608]. Q heads (h<28) are
// pre-scaled by SCALE*LOG2E so attention scores come out in exp2-domain.
__global__ void __launch_bounds__(256) rope_apply(short* __restrict__ qkv,
                                                  const float* __restrict__ ctab,
                                                  const float* __restrict__ stab) {
  const int idx = blockIdx.x * 256 + threadIdx.x;  // 2048*32*8
  const int c = idx & 7;
  const int h = (idx >> 3) & 31;
  const int s = idx >> 8;
  const float qs = (h < 28) ? (0.08838834764831845f * LOG2E) : 1.0f;
  short* base = qkv + (size_t)s * 4608 + h * 128 + c * 8;
  bf16x8 lo = *(bf16x8*)base;
  bf16x8 hi = *(bf16x8*)(base + 64);
  const float* cp = ctab + s * 64 + c * 8;
  const float* sp = stab + s * 64 + c * 8;
  bf16x8 lo2, hi2;
#pragma unroll
  for (int j = 0; j < 8; ++j) {
    const float x = bf2f(lo[j]), y = bf2f(hi[j]);
    const float cv = cp[j], sv = sp[j];
    lo2[j] = f2bf((x * cv - y * sv) * qs);
    hi2[j] = f2bf((y * cv + x * sv) * qs);
  }
  *(bf16x8*)base = lo2;
  *(bf16x8*)(base + 64) = hi2;
}

// V region of qkv -> V^T [4][128][2048]
__global__ void __launch_bounds__(256) v_transpose(const short* __restrict__ qkv,
                                                   short* __restrict__ vtb) {
  __shared__ short t[64 * 48];
  const int dt = blockIdx.x, st = blockIdx.y, kv = blockIdx.z;
  const int tid = threadIdx.x;
  {
    const int r = tid >> 2, c8 = tid & 3;
    const bf16x8 v = *(const bf16x8*)(qkv + (size_t)(st * 64 + r) * 4608 + 4096 +
                                      kv * 128 + dt * 32 + c8 * 8);
    *(bf16x8*)(t + r * 48 + c8 * 8) = v;
  }
  __syncthreads();
  {
    const int d = tid >> 3, c = tid & 7;
    bf16x8 v;
#pragma unroll
    for (int i = 0; i < 8; ++i) v[i] = t[(c * 8 + i) * 48 + d];
    *(bf16x8*)(vtb + ((size_t)kv * 128 + dt * 32 + d) * 2048 + st * 64 + c * 8) = v;
  }
}

// --- 8-phase bf16 GEMM, read-ahead tails (m201-faithful interleave) ---------
// C[M=2048,N] = A[M,K]*B[N,K]^T (+bias). BMx256 tile, 8 waves (2M x 4N),
// BK=64, 2 K-tiles/iter double-buffered.
// Phase = {bar; lgkmcnt(0); sched_barrier; 16 MFMA setprio'd;
//          tail: STG -> [VMW] -> READ frags for NEXT phase}.
// Frag read schedule (no reads between barrier and MFMA — latency hidden):
//   P8t:{af00,b00} P1t:{b01} P2t:{af01} P4t:{af10,b10} P5t:{b11} P6t:{af11}
// Cross-wave vmcnt rule: a tail READ of staged data requires every wave's
// VMW + one barrier in between -> VMW sits at P3/P7 tails (vmcnt(ACH+2):
// drains the OTHER buffer's staging, keeps this iter's t2/t3 loads in
// flight); buf-crossing READs at P4/P8 tails. Last iter: P3 tail vmcnt(0)
// (P8-prev staging of buf1 still in flight otherwise — ledger).
// STG ledger unchanged (region's last read >= 1 phase before its STG).
template <int BM, int NT, int MCH, int NCH, bool BIAS, bool OUTBF>
__global__ void __launch_bounds__(512, 2)
gemm10(const short* __restrict__ A, const short* __restrict__ B,
       const float* __restrict__ bias, void* __restrict__ outp, int N, int K) {
  constexpr int MQ2 = BM / 64;     // m-frags per rh-half (256->4, 128->2)
  constexpr int ACH = BM / 128;    // gll16 calls per A half-tile
  __shared__ short As[2][BM * 64];
  __shared__ short Bs[2][256 * 64];
  const int bid = (int)blockIdx.x;
  const int xcd = bid & 7, idx = bid >> 3;
  const int rowg = xcd / (NT / NCH), colg = xcd % (NT / NCH);
  const int tm = (rowg * MCH + idx % MCH) * BM;
  const int tn = (colg * NCH + idx / MCH) * 256;
  const int tid = (int)threadIdx.x;
  const int wave = tid >> 6, lane = tid & 63;
  const int l15 = lane & 15, g = lane >> 4;
  const int wm = wave >> 2, wn = wave & 3;

  f32x4 acc[2][MQ2][2][2] = {};  // [rh][mq][ch][nq]
  bf16x8 af[MQ2][2], b0[2][2], b1[2][2];

#define STG_A(b, kt, h)                                                         \
  { _Pragma("unroll") for (int j = 0; j < ACH; ++j) {                           \
      const int lr = (h) * (BM / 2) + j * 64 + (tid >> 3);                      \
      const int wmm = (lr / (BM / 4)) & 1;                                      \
      const int rr = lr & (BM / 4 - 1);                                         \
      const int grow = wmm * (BM / 2) + (h) * (BM / 4) + rr;                    \
      const int sc = (tid & 7) ^ (rr & 7);                                      \
      gll16(A + (size_t)(tm + grow) * K + (size_t)(kt) * 64 + sc * 8,           \
            &As[b][((h) * (BM / 2) + j * 64 + wave * 8) * 64]);                 \
    } }
#define STG_B(b, kt, h)                                                         \
  { _Pragma("unroll") for (int j = 0; j < 2; ++j) {                             \
      const int lr = (h) * 128 + j * 64 + (tid >> 3);                           \
      const int wnn = (lr >> 5) & 3;                                            \
      const int rr = lr & 31;                                                   \
      const int gcol = wnn * 64 + (h) * 32 + rr;                                \
      const int sc = (tid & 7) ^ (rr & 7);                                      \
      gll16(B + (size_t)(tn + gcol) * K + (size_t)(kt) * 64 + sc * 8,           \
            &Bs[b][((h) * 128 + j * 64 + wave * 8) * 64]);                      \
    } }
#define LDA(buf, rh)                                                            \
  { _Pragma("unroll") for (int mq = 0; mq < MQ2; ++mq)                          \
      _Pragma("unroll") for (int ks = 0; ks < 2; ++ks) {                        \
        const int lr = (rh) * (BM / 2) + wm * (BM / 4) + mq * 16 + l15;         \
        af[mq][ks] =                                                            \
            *(const bf16x8*)(&As[buf][lr * 64 + (((ks * 4 + g) ^ (lr & 7)) * 8)]); \
      } }
#define LDB(buf, ch, ARR)                                                       \
  { _Pragma("unroll") for (int nq = 0; nq < 2; ++nq)                            \
      _Pragma("unroll") for (int ks = 0; ks < 2; ++ks) {                        \
        const int lr = (ch) * 128 + wn * 32 + nq * 16 + l15;                    \
        ARR[nq][ks] =                                                           \
            *(const bf16x8*)(&Bs[buf][lr * 64 + (((ks * 4 + g) ^ (lr & 7)) * 8)]); \
      } }
#define VMW()                                                                   \
  { if constexpr (ACH == 2) { asm volatile("s_waitcnt vmcnt(4)" ::: "memory"); }\
    else { asm volatile("s_waitcnt vmcnt(3)" ::: "memory"); } }
#define PH(RH, CH, BARR, TAILBLK)                                               \
  {                                                                             \
    __builtin_amdgcn_s_barrier();                                               \
    asm volatile("s_waitcnt lgkmcnt(0)" ::: "memory");                          \
    __builtin_amdgcn_sched_barrier(0);                                          \
    __builtin_amdgcn_s_setprio(1);                                              \
    _Pragma("unroll") for (int mq = 0; mq < MQ2; ++mq)                          \
      _Pragma("unroll") for (int nq = 0; nq < 2; ++nq) {                        \
        acc[RH][mq][CH][nq] = MFMA16(af[mq][0], BARR[nq][0], acc[RH][mq][CH][nq]); \
        acc[RH][mq][CH][nq] = MFMA16(af[mq][1], BARR[nq][1], acc[RH][mq][CH][nq]); \
      }                                                                         \
    __builtin_amdgcn_s_setprio(0);                                              \
    TAILBLK;                                                                    \
    __builtin_amdgcn_sched_barrier(0);                                          \
  }

  // prologue: stage t0+t1; wait t0 landed (2ACH+4 newest = t1 in flight);
  // barrier (cross-wave); read P1's frags.
  STG_A(0, 0, 0); STG_A(0, 0, 1); STG_B(0, 0, 0); STG_B(0, 0, 1);
  STG_A(1, 1, 0); STG_A(1, 1, 1); STG_B(1, 1, 0); STG_B(1, 1, 1);
  if constexpr (ACH == 2) { asm volatile("s_waitcnt vmcnt(8)" ::: "memory"); }
  else                    { asm volatile("s_waitcnt vmcnt(6)" ::: "memory"); }
  __builtin_amdgcn_s_barrier();
  LDA(0, 0); LDB(0, 0, b0);

  const int L = K >> 7;  // 28 iterations, 2 K-tiles each
  for (int i = 0; i < L; ++i) {
    const int t2 = 2 * i + 2, t3 = 2 * i + 3;
    const bool more = (i < L - 1);
    PH(0, 0, b0, { LDB(0, 1, b1); });
    PH(0, 1, b1, { if (more) STG_A(0, t2, 0); LDA(0, 1); });
    PH(1, 1, b1, { if (more) { STG_B(0, t2, 1); VMW(); }
                   else { asm volatile("s_waitcnt vmcnt(0)" ::: "memory"); } });
    PH(1, 0, b0, { if (more) { STG_A(0, t2, 1); STG_B(0, t2, 0); }
                   LDA(1, 0); LDB(1, 0, b0); });
    PH(0, 0, b0, { LDB(1, 1, b1); });
    PH(0, 1, b1, { if (more) STG_A(1, t3, 0); LDA(1, 1); });
    PH(1, 1, b1, { if (more) { STG_B(1, t3, 1); VMW(); } });
    PH(1, 0, b0, { if (more) { STG_A(1, t3, 1); STG_B(1, t3, 0);
                               LDA(0, 0); LDB(0, 0, b0); } });
  }
#undef STG_A
#undef STG_B
#undef LDA
#undef LDB
#undef VMW
#undef PH

  // epilogue: 16x16 C/D layout col=lane&15, row=(lane>>4)*4+reg
#pragma unroll
  for (int rh = 0; rh < 2; ++rh)
#pragma unroll
    for (int mq = 0; mq < MQ2; ++mq)
#pragma unroll
      for (int ch = 0; ch < 2; ++ch)
#pragma unroll
        for (int nq = 0; nq < 2; ++nq) {
          const int col = tn + wn * 64 + ch * 32 + nq * 16 + l15;
          const float bv = BIAS ? bias[col] : 0.0f;
          const int row0 = tm + wm * (BM / 2) + rh * (BM / 4) + mq * 16 + g * 4;
#pragma unroll
          for (int r = 0; r < 4; ++r) {
            const float v = acc[rh][mq][ch][nq][r] + bv;
            if (OUTBF) ((short*)outp)[(size_t)(row0 + r) * N + col] = f2bf(v);
            else       ((float*)outp)[(size_t)(row0 + r) * N + col] = v;
          }
        }
}

// ---------------- flash attention, 2-phase pipelined, paired q-tiles --------
__global__ void __launch_bounds__(256) attn_kernel(const short* __restrict__ qkv,
                                                   const short* __restrict__ vtb,
                                                   short* __restrict__ outb) {
  const int lid = (int)blockIdx.x + ((int)blockIdx.y << 4);
  const int kvh = (lid & 7) >> 1;
  const int u = ((lid >> 3) << 1) + (lid & 1);  // 0..111 within kv group
  const int head = kvh * 7 + (u >> 4);
  const int qtA = u & 15, qtB = 31 - qtA;

  const int tid = threadIdx.x;
  const int lane = tid & 63, wave = tid >> 6;
  const int l15 = lane & 15, g = lane >> 4;

  __shared__ short Ks[2][64 * 128];
  __shared__ short Vs[2][128 * 64];
  __shared__ short Ps[4][16 * 64];

  const short* kbase = qkv + 3584 + kvh * 128;
  const short* vbase = vtb + (size_t)kvh * 128 * 2048;
  const float NINF = -__builtin_inff();

  bf16x8 qf[4];
  f32x4 o[8];
  float mrun[4], lrun[4];

#define LOADQ(qt)                                                                  \
  {                                                                                \
    const short* qptr =                                                            \
        qkv + (size_t)((qt)*64 + wave * 16 + l15) * 4608 + head * 128 + g * 8;     \
    _Pragma("unroll") for (int ds = 0; ds < 4; ++ds) qf[ds] =                      \
        *(const bf16x8*)(qptr + ds * 32);                                          \
  }
#define RESET()                                                                    \
  {                                                                                \
    _Pragma("unroll") for (int nd = 0; nd < 8; ++nd) o[nd] = f32x4{0.f,0.f,0.f,0.f}; \
    _Pragma("unroll") for (int r = 0; r < 4; ++r) { mrun[r] = NINF; lrun[r] = 0.f; } \
  }
#define STAGE(kv, b)                                                               \
  {                                                                                \
    _Pragma("unroll") for (int it = 0; it < 4; ++it) {                             \
      const int chunk = it * 256 + tid;                                            \
      const int row = chunk >> 4, sc = (chunk & 15) ^ (row & 7);                   \
      gll16(kbase + (size_t)((kv)*64 + row) * 4608 + sc * 8,                       \
            &Ks[b][(it * 256 + wave * 64) * 8]);                                   \
    }                                                                              \
    _Pragma("unroll") for (int it = 0; it < 4; ++it) {                             \
      const int chunk = it * 256 + tid;                                            \
      const int row = chunk >> 3, sc = (chunk & 7) ^ (row & 7);                    \
      gll16(vbase + (size_t)row * 2048 + (kv)*64 + sc * 8,                         \
            &Vs[b][(it * 256 + wave * 64) * 8]);                                   \
    }                                                                              \
  }

  RESET();
  LOADQ(qtA);
  STAGE(0, 0);
  __syncthreads();
  int cur = 0;

  for (int s = 0; s < 33; ++s) {
    if (s < 32) {
      const int sn = s + 1;
      const int kvn = (sn <= qtA) ? sn : sn - qtA - 1;
      STAGE(kvn, cur ^ 1);
    }
    const int qt = (s <= qtA) ? qtA : qtB;
    const int kv = (s <= qtA) ? s : s - qtA - 1;
    const bool diag = (s == qtA) || (s == 32);

    f32x4 sf[4] = {};
    __builtin_amdgcn_s_setprio(1);
#pragma unroll
    for (int n = 0; n < 4; ++n) {
      const int krow = n * 16 + l15;
#pragma unroll
      for (int ds = 0; ds < 4; ++ds) {
        const int c = (ds * 4 + g) ^ (krow & 7);
        const bf16x8 kf = *(const bf16x8*)(&Ks[cur][krow * 128 + c * 8]);
        sf[n] = MFMA16(qf[ds], kf, sf[n]);
      }
    }
    __builtin_amdgcn_s_setprio(0);

    if (diag) {
#pragma unroll
      for (int r = 0; r < 4; ++r) {
        const int qr = qt * 64 + wave * 16 + g * 4 + r;
#pragma unroll
        for (int n = 0; n < 4; ++n)
          if (kv * 64 + n * 16 + l15 > qr) sf[n][r] = NINF;
      }
    }
    float pmax[4];
#pragma unroll
    for (int r = 0; r < 4; ++r)
      pmax[r] = fmaxf(fmaxf(sf[0][r], sf[1][r]), fmaxf(sf[2][r], sf[3][r]));
    const bool need = (pmax[0] > mrun[0] + 8.f) || (pmax[1] > mrun[1] + 8.f) ||
                      (pmax[2] > mrun[2] + 8.f) || (pmax[3] > mrun[3] + 8.f);
    if (__any(need)) {
#pragma unroll
      for (int r = 0; r < 4; ++r) {
        float mx = pmax[r];
        mx = fmaxf(mx, __shfl_xor(mx, 1));
        mx = fmaxf(mx, __shfl_xor(mx, 2));
        mx = fmaxf(mx, __shfl_xor(mx, 4));
        mx = fmaxf(mx, __shfl_xor(mx, 8));
        const float mnew = fmaxf(mrun[r], mx);
        const float alpha = exp2f(mrun[r] - mnew);
        mrun[r] = mnew;
        lrun[r] *= alpha;
#pragma unroll
        for (int nd = 0; nd < 8; ++nd) o[nd][r] *= alpha;
      }
    }
#pragma unroll
    for (int n = 0; n < 4; ++n) {
#pragma unroll
      for (int r = 0; r < 4; ++r) {
        const float p = exp2f(sf[n][r] - mrun[r]);
        lrun[r] += p;
        const int prow = g * 4 + r, key = n * 16 + l15;
        const int cp = (key >> 3) ^ (prow & 7);
        Ps[wave][prow * 64 + cp * 8 + (key & 7)] = f2bf(p);
      }
    }
    bf16x8 pf[2];
#pragma unroll
    for (int ksl = 0; ksl < 2; ++ksl) {
      const int c = (ksl * 4 + g) ^ (l15 & 7);
      pf[ksl] = *(const bf16x8*)(&Ps[wave][l15 * 64 + c * 8]);
    }
    __builtin_amdgcn_s_setprio(1);
#pragma unroll
    for (int nd = 0; nd < 8; ++nd) {
      const int vrow = nd * 16 + l15;
#pragma unroll
      for (int ksl = 0; ksl < 2; ++ksl) {
        const int c = (ksl * 4 + g) ^ (vrow & 7);
        const bf16x8 vf = *(const bf16x8*)(&Vs[cur][vrow * 64 + c * 8]);
        o[nd] = MFMA16(pf[ksl], vf, o[nd]);
      }
    }
    __builtin_amdgcn_s_setprio(0);

    if (diag) {
      float inv[4];
#pragma unroll
      for (int r = 0; r < 4; ++r) {
        float sum = lrun[r];
        sum += __shfl_xor(sum, 1);
        sum += __shfl_xor(sum, 2);
        sum += __shfl_xor(sum, 4);
        sum += __shfl_xor(sum, 8);
        inv[r] = 1.0f / sum;
      }
#pragma unroll
      for (int nd = 0; nd < 8; ++nd) {
#pragma unroll
        for (int r = 0; r < 4; ++r) {
          const int qr = qt * 64 + wave * 16 + g * 4 + r;
          outb[(size_t)qr * 3584 + head * 128 + nd * 16 + l15] = f2bf(o[nd][r] * inv[r]);
        }
      }
      if (s == qtA) {
        RESET();
        LOADQ(qtB);
      }
    }
    __syncthreads();
    cur ^= 1;
  }
#undef LOADQ
#undef RESET
#undef STAGE
}

extern "C" void kernel_launch(void* const* d_in, const int* in_sizes, int n_in,
                              void* d_out, int out_size, void* d_ws, size_t ws_size,
                              hipStream_t stream) {
  const float* h  = (const float*)d_in[0];
  const int* pos  = (const int*)d_in[1];
  const float* Wq = (const float*)d_in[2];
  const float* bq = (const float*)d_in[3];
  const float* Wk = (const float*)d_in[4];
  const float* bk = (const float*)d_in[5];
  const float* Wv = (const float*)d_in[6];
  const float* bv = (const float*)d_in[7];
  const float* Wo = (const float*)d_in[8];
  float* out = (float*)d_out;

  char* w = (char*)d_ws;
  short* hbf  = (short*)w; w += (size_t)2048 * 3584 * 2;
  short* Wall = (short*)w; w += (size_t)4608 * 3584 * 2;
  float* ball = (float*)w; w += 4608 * 4;
  short* qkvp = (short*)w; w += (size_t)2048 * 4608 * 2;
  float* ctab = (float*)w; w += 2048 * 64 * 4;
  float* stab = (float*)w; w += 2048 * 64 * 4;
  short* vtb  = (short*)w; w += (size_t)4 * 128 * 2048 * 2;
  short* attnb = hbf;
  short* Wob = Wall;

  cvt_kernel<<<2048, 256, 0, stream>>>(h, hbf, (long long)2048 * 3584);
  cvt_kernel<<<2048, 256, 0, stream>>>(Wq, Wall, (long long)3584 * 3584);
  cvt_kernel<<<512, 256, 0, stream>>>(Wk, Wall + (size_t)3584 * 3584, (long long)512 * 3584);
  cvt_kernel<<<512, 256, 0, stream>>>(Wv, Wall + (size_t)4096 * 3584, (long long)512 * 3584);
  bias_concat<<<18, 256, 0, stream>>>(bq, bk, bv, ball);
  rope_table<<<2048, 64, 0, stream>>>(pos, ctab, stab);

  gemm10<256, 18, 2, 9, true, true><<<144, 512, 0, stream>>>(hbf, Wall, ball, qkvp, 4608, 3584);
  rope_apply<<<2048, 256, 0, stream>>>(qkvp, ctab, stab);
  v_transpose<<<dim3(4, 32, 4), 256, 0, stream>>>(qkvp, vtb);
  cvt_kernel<<<2048, 256, 0, stream>>>(Wo, Wob, (long long)3584 * 3584);

  attn_kernel<<<dim3(16, 28), 256, 0, stream>>>(qkvp, vtb, attnb);

  gemm10<128, 14, 4, 7, false, false><<<224, 512, 0, stream>>>(attnb, Wob, nullptr, out, 3584, 3584);
}